// Round 6
// baseline (3460.098 us; speedup 1.0000x reference)
//
#include <hip/hip_runtime.h>
#include <hip/hip_bf16.h>
#include <math.h>

#define NN 1764
#define SORTN 2048

// ---------------- weight packing ----------------
// 3x3 convs:  W[co][ci][3][3] -> Wp[ci][co][12]  (9 taps + 3 pad)
template<int Co, int Ci>
__device__ inline void seg_pack(const float* __restrict__ src, float* __restrict__ dst, int i) {
  int co = i / (Ci * 9); int rem = i - co * (Ci * 9); int ci = rem / 9; int k = rem - ci * 9;
  dst[((size_t)ci * Co + co) * 12 + k] = src[i];
}
template<int Co, int CiK>
__device__ inline void seg_tr(const float* __restrict__ src, float* __restrict__ dst, int i) {
  int co = i / CiK; int cik = i - co * CiK;
  dst[cik * Co + co] = src[i];
}

__global__ void wtrans_all(
  const float* __restrict__ b1w, const float* __restrict__ c1w,
  const float* __restrict__ b2w, const float* __restrict__ c2w,
  const float* __restrict__ b3w, const float* __restrict__ b4w,
  const float* __restrict__ c3w,
  float* __restrict__ wp1b, float* __restrict__ wp1c,
  float* __restrict__ wp2b, float* __restrict__ wp2c,
  float* __restrict__ wp3b, float* __restrict__ wt4b, float* __restrict__ wt3c)
{
  int j = blockIdx.x * blockDim.x + threadIdx.x;
  if (j < 1179648) { seg_pack<256, 512>(b1w, wp1b, j); return; } j -= 1179648;
  if (j < 1179648) { seg_pack<256, 512>(c1w, wp1c, j); return; } j -= 1179648;
  if (j < 294912)  { seg_pack<128, 256>(b2w, wp2b, j); return; } j -= 294912;
  if (j < 294912)  { seg_pack<128, 256>(c2w, wp2c, j); return; } j -= 294912;
  if (j < 147456)  { seg_pack<128, 128>(b3w, wp3b, j); return; } j -= 147456;
  if (j < 4608)    { seg_tr<36, 128>(b4w, wt4b, j); return; }  j -= 4608;
  if (j < 1152)    { seg_tr<9, 128>(c3w, wt3c, j); return; }
}

// ---------------- pad features [B][C][196] -> [B][C][16][16] zero-halo ----------------
__global__ __launch_bounds__(256) void pad_in(const float* __restrict__ in,
                                              float* __restrict__ out)
{
  int idx = blockIdx.x * 256 + threadIdx.x;    // over B*C*256
  int cell = idx & 255, ch = idx >> 8;
  int ly = cell >> 4, lx = cell & 15;
  bool inter = (ly >= 1) && (ly <= 14) && (lx >= 1) && (lx <= 14);
  float v = 0.0f;
  if (inter) v = in[ch * 196 + (ly - 1) * 14 + (lx - 1)];
  out[idx] = v;
}

// ---------------- split-K conv3x3, NO LDS: direct padded-global reads ----------------
// Lane: col = tid&15 (co), r = tid>>4 (row, active r<14). COPT=4 channels/lane.
// Ping-pong prefetch: rows (nbb[2][12]) double-buffered per ci, weights (wbuf[2][3])
// per c-group. No barriers in K-loop; latency hidden by explicit prefetch + 2 waves/SIMD.
#define FMA_GROUP(C, PH)                                                         \
  {                                                                              \
    const float4 W0 = wbuf[(C) & 1][0], W1 = wbuf[(C) & 1][1], W2 = wbuf[(C) & 1][2]; \
    const float wk0 = W0.x, wk1 = W0.y, wk2 = W0.z;                              \
    const float wk3 = W0.w, wk4 = W1.x, wk5 = W1.y;                              \
    const float wk6 = W1.z, wk7 = W1.w, wk8 = W2.x;                              \
    _Pragma("unroll")                                                            \
    for (int j = 0; j < 14; ++j) {                                               \
      float t = acc[C][j];                                                       \
      t = fmaf(wk0, nbf[0][j + 0], t);                                           \
      t = fmaf(wk1, nbf[0][j + 1], t);                                           \
      t = fmaf(wk2, nbf[0][j + 2], t);                                           \
      t = fmaf(wk3, nbf[1][j + 0], t);                                           \
      t = fmaf(wk4, nbf[1][j + 1], t);                                           \
      t = fmaf(wk5, nbf[1][j + 2], t);                                           \
      t = fmaf(wk6, nbf[2][j + 0], t);                                           \
      t = fmaf(wk7, nbf[2][j + 1], t);                                           \
      t = fmaf(wk8, nbf[2][j + 2], t);                                           \
      acc[C][j] = t;                                                             \
    }                                                                            \
  }

#define LOAD_NB(PH, PTR)                                                         \
  {                                                                              \
    _Pragma("unroll")                                                            \
    for (int dr = 0; dr < 3; ++dr) {                                             \
      const float4* rp_ = (const float4*)((PTR) + dr * 16);                      \
      nbb[PH][dr * 4 + 0] = rp_[0]; nbb[PH][dr * 4 + 1] = rp_[1];                \
      nbb[PH][dr * 4 + 2] = rp_[2]; nbb[PH][dr * 4 + 3] = rp_[3];                \
    }                                                                            \
  }

#define EXTRACT_NB(PH)                                                           \
  float nbf[3][16];                                                              \
  {                                                                              \
    _Pragma("unroll")                                                            \
    for (int dr = 0; dr < 3; ++dr) {                                             \
      float4 a_ = nbb[PH][dr * 4 + 0], b_ = nbb[PH][dr * 4 + 1];                 \
      float4 c_ = nbb[PH][dr * 4 + 2], d_ = nbb[PH][dr * 4 + 3];                 \
      nbf[dr][0]  = a_.x; nbf[dr][1]  = a_.y; nbf[dr][2]  = a_.z; nbf[dr][3]  = a_.w; \
      nbf[dr][4]  = b_.x; nbf[dr][5]  = b_.y; nbf[dr][6]  = b_.z; nbf[dr][7]  = b_.w; \
      nbf[dr][8]  = c_.x; nbf[dr][9]  = c_.y; nbf[dr][10] = c_.z; nbf[dr][11] = c_.w; \
      nbf[dr][12] = d_.x; nbf[dr][13] = d_.y; nbf[dr][14] = d_.z; nbf[dr][15] = d_.w; \
    }                                                                            \
  }

#define LOAD_W(SLOT, PTR)                                                        \
  { const float4* wq_ = (const float4*)(PTR);                                    \
    wbuf[SLOT][0] = wq_[0]; wbuf[SLOT][1] = wq_[1]; wbuf[SLOT][2] = wq_[2]; }

// body for one ci at phase PH (nbb buffer). ipb/wpb = this ci's bases.
// MOREW: prefetch target (next ci's c0) exists; MORENB: next-next rows exist.
#define CI_BODY(PH, IPB, WPB, MOREW, MORENB, NBTGT, NBPTR)                       \
  {                                                                              \
    EXTRACT_NB(PH)                                                               \
    /* c = 0 : uses wbuf[0], prefetch wbuf[1] = (ci,c1) */                       \
    LOAD_W(1, (WPB) + 192)                                                       \
    FMA_GROUP(0, PH)                                                             \
    /* c = 1 : uses wbuf[1], prefetch wbuf[0] = (ci,c2) */                       \
    LOAD_W(0, (WPB) + 384)                                                       \
    FMA_GROUP(1, PH)                                                             \
    /* c = 2 : uses wbuf[0], prefetch wbuf[1] = (ci,c3); prefetch next rows */   \
    LOAD_W(1, (WPB) + 576)                                                       \
    if (MORENB) { LOAD_NB(NBTGT, NBPTR) }                                        \
    FMA_GROUP(2, PH)                                                             \
    /* c = 3 : uses wbuf[1], prefetch wbuf[0] = (ci+1,c0) */                     \
    if (MOREW) { LOAD_W(0, (WPB) + wstep) }                                      \
    FMA_GROUP(3, PH)                                                             \
  }

template<int COPT>
__global__ __launch_bounds__(256, 2) void conv3x3_direct(
    const float* __restrict__ in0, const float* __restrict__ in1,
    const float* __restrict__ wt0, const float* __restrict__ wt1,
    float* __restrict__ po0, float* __restrict__ po1,
    int Cin, int Cout, int cobPerHead, int cinPerSplit, size_t sStride)
{
  const int tid = threadIdx.x;
  const int bx  = blockIdx.x;
  const int b   = blockIdx.y;
  const int s   = blockIdx.z;
  const int head = bx / cobPerHead;
  const int cob  = bx - head * cobPerHead;
  const float* in  = head ? in1  : in0;
  const float* wt  = head ? wt1  : wt0;
  float* po        = head ? po1  : po0;
  const int co0 = cob * (16 * COPT);

  const int col = tid & 15;
  const int r   = tid >> 4;
  const int co  = co0 + col;
  const bool ract = r < 14;

  const int ci0 = s * cinPerSplit;
  const int n   = cinPerSplit;             // even (256 / 64 / 16)
  const int wstep = Cout * 12;

  const float* ip = in + ((size_t)b * Cin + ci0) * 256 + r * 16;
  const float* wp = wt + ((size_t)ci0 * Cout + co) * 12;

  float acc[COPT][14];
#pragma unroll
  for (int c = 0; c < COPT; ++c)
#pragma unroll
    for (int j = 0; j < 14; ++j) acc[c][j] = 0.0f;

  float4 nbb[2][12];
  float4 wbuf[2][3];

  // prologue: rows + first weight group for ci=0
  LOAD_NB(0, ip)
  LOAD_W(0, wp)

  for (int ci = 0; ci < n; ci += 2) {
    const bool morePair = (ci + 2 < n);
    // phase 0: ci       (rows nbb[0]); prefetch rows ci+1 -> nbb[1] (always valid)
    CI_BODY(0, ip, wp, true, true, 1, ip + 256)
    // phase 1: ci+1     (rows nbb[1]); prefetch rows ci+2 -> nbb[0] if exists
    CI_BODY(1, ip + 256, wp + wstep, morePair, morePair, 0, ip + 512)
    ip += 512;
    wp += 2 * wstep;
  }

  if (ract) {
#pragma unroll
    for (int c = 0; c < COPT; ++c) {
      const int oc = c * 16 + col;
      float* op = po + (size_t)s * sStride + ((size_t)b * Cout + co0 + oc) * 196 + r * 14;
#pragma unroll
      for (int j = 0; j < 14; ++j) op[j] = acc[c][j];
    }
  }
}

// ---------------- combine partials + bias + GELU + GN; writes PADDED layout ----------------
template<int S>
__global__ __launch_bounds__(256) void combine_gn(
    const float* __restrict__ po0, const float* __restrict__ po1,
    const float* __restrict__ bs0, const float* __restrict__ bs1,
    const float* __restrict__ gw0, const float* __restrict__ gw1,
    const float* __restrict__ gb0, const float* __restrict__ gb1,
    float* __restrict__ out0, float* __restrict__ out1,
    int Cout, int cobPerHead, size_t sStride)
{
  const int tid = threadIdx.x, bx = blockIdx.x, b = blockIdx.y;
  const int head = bx / cobPerHead, cob = bx - head * cobPerHead;
  const float* po = head ? po1 : po0;
  const float* bs = head ? bs1 : bs0;
  const float* gw = head ? gw1 : gw0;
  const float* gb = head ? gb1 : gb0;
  float* out      = head ? out1 : out0;
  const int co0 = cob * 16;

  __shared__ float red[4][4];
  __shared__ float stats[4];

  const int ly = tid >> 4, lx = tid & 15;
  const bool inter = (ly >= 1) && (ly <= 14) && (lx >= 1) && (lx <= 14);
  const int p = (ly - 1) * 14 + (lx - 1);

  float v[16];
  float s0 = 0.f, q0 = 0.f, s1 = 0.f, q1 = 0.f;
  if (inter) {
#pragma unroll
    for (int c = 0; c < 16; ++c) {
      const size_t base = ((size_t)b * Cout + co0 + c) * 196 + p;
      float x = bs[co0 + c];
#pragma unroll
      for (int s = 0; s < S; ++s) x += po[base + (size_t)s * sStride];
      float g = 0.5f * x * (1.0f + erff(x * 0.70710678118654752440f));
      v[c] = g;
      if (c < 8) { s0 += g; q0 += g * g; } else { s1 += g; q1 += g * g; }
    }
  }
#pragma unroll
  for (int off = 32; off > 0; off >>= 1) {
    s0 += __shfl_down(s0, off, 64); q0 += __shfl_down(q0, off, 64);
    s1 += __shfl_down(s1, off, 64); q1 += __shfl_down(q1, off, 64);
  }
  const int wave = tid >> 6, lane = tid & 63;
  if (lane == 0) { red[wave][0] = s0; red[wave][1] = q0; red[wave][2] = s1; red[wave][3] = q1; }
  __syncthreads();
  if (tid == 0) {
    float S0 = red[0][0] + red[1][0] + red[2][0] + red[3][0];
    float Q0 = red[0][1] + red[1][1] + red[2][1] + red[3][1];
    float S1 = red[0][2] + red[1][2] + red[2][2] + red[3][2];
    float Q1 = red[0][3] + red[1][3] + red[2][3] + red[3][3];
    float m0 = S0 * (1.0f / 1568.0f);
    float v0 = Q0 * (1.0f / 1568.0f) - m0 * m0;
    float m1 = S1 * (1.0f / 1568.0f);
    float v1 = Q1 * (1.0f / 1568.0f) - m1 * m1;
    stats[0] = m0; stats[1] = 1.0f / sqrtf(v0 + 1e-5f);
    stats[2] = m1; stats[3] = 1.0f / sqrtf(v1 + 1e-5f);
  }
  __syncthreads();
  float m0 = stats[0], i0 = stats[1], m1 = stats[2], i1 = stats[3];
#pragma unroll
  for (int c = 0; c < 16; ++c) {
    float y = 0.0f;
    if (inter) {
      float m  = (c < 8) ? m0 : m1;
      float iv = (c < 8) ? i0 : i1;
      y = (v[c] - m) * iv * gw[co0 + c] + gb[co0 + c];
    }
    out[((size_t)b * Cout + co0 + c) * 256 + tid] = y;   // padded [16][16] layout
  }
}

// ---------------- 1x1 heads (inputs in PADDED layout) ----------------
__global__ __launch_bounds__(256) void heads_1x1(
    const float* __restrict__ tb, const float* __restrict__ tc,
    const float* __restrict__ wtb, const float* __restrict__ wtc,
    const float* __restrict__ bb,  const float* __restrict__ bc,
    float* __restrict__ bbox, float* __restrict__ conf)
{
  const int b = blockIdx.x, tid = threadIdx.x;
  if (tid >= 196) return;
  const int p = tid;
  const int prow = p / 14, pcol = p - prow * 14;
  const int pp = (prow + 1) * 16 + (pcol + 1);
  float ab[36], ac[9];
#pragma unroll
  for (int o = 0; o < 36; ++o) ab[o] = bb[o];
#pragma unroll
  for (int o = 0; o < 9; ++o) ac[o] = bc[o];
  const float* pb = tb + (size_t)b * 128 * 256 + pp;
  const float* pc = tc + (size_t)b * 128 * 256 + pp;
  for (int ci = 0; ci < 128; ++ci) {
    float xb = pb[ci * 256];
    float xc = pc[ci * 256];
    const float* wb = wtb + ci * 36;
    const float* wc = wtc + ci * 9;
#pragma unroll
    for (int o = 0; o < 36; ++o) ab[o] = fmaf(wb[o], xb, ab[o]);
#pragma unroll
    for (int o = 0; o < 9; ++o)  ac[o] = fmaf(wc[o], xc, ac[o]);
  }
  const size_t nb = (size_t)b * NN;
#pragma unroll
  for (int a = 0; a < 9; ++a) {
    size_t n = nb + (size_t)p * 9 + a;
#pragma unroll
    for (int d = 0; d < 4; ++d) bbox[n * 4 + d] = ab[a * 4 + d];
    conf[n] = 1.0f / (1.0f + expf(-ac[a]));
  }
}

// ---------------- per-image greedy NMS with early exit at 50 kept ----------------
__global__ __launch_bounds__(256) void nms_kernel(
  const float* __restrict__ bbox, const float* __restrict__ conf, float* __restrict__ out)
{
  const int b = blockIdx.x, tid = threadIdx.x;
  __shared__ unsigned long long key[SORTN];
  __shared__ float sx1[NN], sy1[NN], sx2[NN], sy2[NN], sar[NN], ssc[NN];
  __shared__ unsigned char sup[NN];
  __shared__ int sV, sMin;

  if (tid == 0) sV = 0;
  __syncthreads();
  int cntv = 0;
  const float* cf = conf + (size_t)b * NN;
  for (int i = tid; i < SORTN; i += 256) {
    unsigned long long k;
    if (i < NN) {
      float s = cf[i];
      unsigned rank = (unsigned)(NN - 1 - i);
      if (s > 0.5f) { k = (((unsigned long long)__float_as_uint(s)) << 32) | rank; cntv++; }
      else k = (unsigned long long)rank;
    } else k = 0ull;
    key[i] = k;
  }
  atomicAdd(&sV, cntv);
  __syncthreads();
  const int V = sV;

  for (int kk = 2; kk <= SORTN; kk <<= 1) {
    for (int j = kk >> 1; j > 0; j >>= 1) {
      for (int i = tid; i < SORTN; i += 256) {
        int ixj = i ^ j;
        if (ixj > i) {
          unsigned long long a = key[i], c = key[ixj];
          bool dirDesc = ((i & kk) == 0);
          if ((a < c) == dirDesc) { key[i] = c; key[ixj] = a; }
        }
      }
      __syncthreads();
    }
  }

  const float* bbb = bbox + (size_t)b * NN * 4;
  for (int i = tid; i < V; i += 256) {
    unsigned long long k = key[i];
    int idx = NN - 1 - (int)(unsigned)(k & 0xFFFFFFFFull);
    float s = __uint_as_float((unsigned)(k >> 32));
    const float* bp = bbb + (size_t)idx * 4;
    float x1 = fminf(fmaxf(bp[0], 0.0f), 1.0f);
    float y1 = fminf(fmaxf(bp[1], 0.0f), 1.0f);
    float x2 = fminf(fmaxf(bp[2], 0.0f), 1.0f);
    float y2 = fminf(fmaxf(bp[3], 0.0f), 1.0f);
    sx1[i] = x1; sy1[i] = y1; sx2[i] = x2; sy2[i] = y2;
    sar[i] = (x2 - x1) * (y2 - y1);
    ssc[i] = s;
    sup[i] = 0;
  }
  __syncthreads();

  int kept = 0, cur = 0;
  float* ob = out + (size_t)b * 50 * 5;
  while (kept < 50 && cur < V) {
    int nxt = -1;
    for (int base = cur; base < V; base += 256) {
      if (tid == 0) sMin = 0x7FFFFFFF;
      __syncthreads();
      int i = base + tid;
      if (i < V && !sup[i]) atomicMin(&sMin, i);
      __syncthreads();
      if (sMin != 0x7FFFFFFF) { nxt = sMin; break; }
    }
    if (nxt < 0) break;
    float kx1 = sx1[nxt], ky1 = sy1[nxt], kx2 = sx2[nxt], ky2 = sy2[nxt], ka = sar[nxt];
    if (tid == 0) {
      float* rr = ob + kept * 5;
      rr[0] = kx1; rr[1] = ky1; rr[2] = kx2; rr[3] = ky2; rr[4] = ssc[nxt];
    }
    kept++;
    for (int jj = nxt + 1 + tid; jj < V; jj += 256) {
      if (!sup[jj]) {
        float xx1 = fmaxf(kx1, sx1[jj]);
        float yy1 = fmaxf(ky1, sy1[jj]);
        float xx2 = fminf(kx2, sx2[jj]);
        float yy2 = fminf(ky2, sy2[jj]);
        float inter = fmaxf(xx2 - xx1, 0.0f) * fmaxf(yy2 - yy1, 0.0f);
        float iou = inter / ((ka + sar[jj]) - inter);
        if (!(iou < 0.3f)) sup[jj] = 1;
      }
    }
    cur = nxt + 1;
    __syncthreads();
  }
  for (int rr = kept + tid; rr < 50; rr += 256) {
    float* qq = ob + rr * 5;
    qq[0] = 0.0f; qq[1] = 0.0f; qq[2] = 0.0f; qq[3] = 0.0f; qq[4] = -1.0f;
  }
}

// ---------------- launch ----------------
extern "C" void kernel_launch(void* const* d_in, const int* in_sizes, int n_in,
                              void* d_out, int out_size, void* d_ws, size_t ws_size,
                              hipStream_t stream)
{
  const float* features = (const float*)d_in[0];
  const float* b1w = (const float*)d_in[1];  const float* b1b = (const float*)d_in[2];
  const float* bg1w = (const float*)d_in[3]; const float* bg1b = (const float*)d_in[4];
  const float* b2w = (const float*)d_in[5];  const float* b2b = (const float*)d_in[6];
  const float* bg2w = (const float*)d_in[7]; const float* bg2b = (const float*)d_in[8];
  const float* b3w = (const float*)d_in[9];  const float* b3b = (const float*)d_in[10];
  const float* bg3w = (const float*)d_in[11]; const float* bg3b = (const float*)d_in[12];
  const float* b4w = (const float*)d_in[13]; const float* b4b = (const float*)d_in[14];
  const float* c1w = (const float*)d_in[15]; const float* c1b = (const float*)d_in[16];
  const float* cg1w = (const float*)d_in[17]; const float* cg1b = (const float*)d_in[18];
  const float* c2w = (const float*)d_in[19]; const float* c2b = (const float*)d_in[20];
  const float* cg2w = (const float*)d_in[21]; const float* cg2b = (const float*)d_in[22];
  const float* c3w = (const float*)d_in[23]; const float* c3b = (const float*)d_in[24];

  float* ws = (float*)d_ws;
  float* wp1b = ws; ws += 1572864;   // 512*256*12
  float* wp1c = ws; ws += 1572864;
  float* wp2b = ws; ws += 393216;    // 256*128*12
  float* wp2c = ws; ws += 393216;
  float* wp3b = ws; ws += 196608;    // 128*128*12
  float* wt4b = ws; ws += 4608;
  float* wt3c = ws; ws += 1152;
  float* fpad = ws; ws += 4194304;   // 32*512*256 padded features
  float* t1b = ws; ws += 2097152;    // 32*256*256 padded
  float* t1c = ws; ws += 2097152;
  float* t2b = ws; ws += 1048576;    // 32*128*256 padded
  float* t2c = ws; ws += 1048576;
  float* t3b = ws; ws += 1048576;
  float* P   = ws; ws += 6422528;    // partial region (aliased across layers)
  float* bbox = ws; ws += 225792;
  float* conf = ws; ws += 56448;

  wtrans_all<<<12119, 256, 0, stream>>>(b1w, c1w, b2w, c2w, b3w, b4w, c3w,
                                        wp1b, wp1c, wp2b, wp2c, wp3b, wt4b, wt3c);
  pad_in<<<16384, 256, 0, stream>>>(features, fpad);   // 32*512 channels

  // conv1: Cin=512, Cout=256, COPT=4, S=2 -> 512 blocks (2/CU), no LDS
  {
    const size_t sStr = (size_t)32 * 256 * 196;        // 1605632
    conv3x3_direct<4><<<dim3(8, 32, 2), 256, 0, stream>>>(
        fpad, fpad, wp1b, wp1c, P, P + 2 * sStr, 512, 256, 4, 256, sStr);
    combine_gn<2><<<dim3(32, 32), 256, 0, stream>>>(
        P, P + 2 * sStr, b1b, c1b, bg1w, cg1w, bg1b, cg1b, t1b, t1c, 256, 16, sStr);
  }
  // conv2: Cin=256, Cout=128, COPT=4, S=4 -> 512 blocks
  {
    const size_t sStr = (size_t)32 * 128 * 196;        // 802816
    conv3x3_direct<4><<<dim3(4, 32, 4), 256, 0, stream>>>(
        t1b, t1c, wp2b, wp2c, P, P + 4 * sStr, 256, 128, 2, 64, sStr);
    combine_gn<4><<<dim3(16, 32), 256, 0, stream>>>(
        P, P + 4 * sStr, b2b, c2b, bg2w, cg2w, bg2b, cg2b, t2b, t2c, 128, 8, sStr);
  }
  // conv3 (bbox only): Cin=128, Cout=128, COPT=4, S=8 -> 512 blocks
  {
    const size_t sStr = (size_t)32 * 128 * 196;
    conv3x3_direct<4><<<dim3(2, 32, 8), 256, 0, stream>>>(
        t2b, t2b, wp3b, wp3b, P, P, 128, 128, 2, 16, sStr);
    combine_gn<8><<<dim3(8, 32), 256, 0, stream>>>(
        P, P, b3b, b3b, bg3w, bg3w, bg3b, bg3b, t3b, t3b, 128, 8, sStr);
  }

  heads_1x1<<<32, 256, 0, stream>>>(t3b, t2c, wt4b, wt3c, b4b, c3b, bbox, conf);
  nms_kernel<<<32, 256, 0, stream>>>(bbox, conf, (float*)d_out);
}

// Round 7
// 913.746 us; speedup vs baseline: 3.7867x; 3.7867x over previous
//
#include <hip/hip_runtime.h>
#include <hip/hip_bf16.h>
#include <math.h>

#define CHUNK 16
#define NN 1764
#define SORTN 2048

// ---------------- weight packing ----------------
// 3x3 convs:  W[co][ci][3][3] -> Wp[ci][co][12]  (9 taps + 3 pad, dwordx4-friendly)
template<int Co, int Ci>
__device__ inline void seg_pack(const float* __restrict__ src, float* __restrict__ dst, int i) {
  int co = i / (Ci * 9); int rem = i - co * (Ci * 9); int ci = rem / 9; int k = rem - ci * 9;
  dst[((size_t)ci * Co + co) * 12 + k] = src[i];
}
template<int Co, int CiK>
__device__ inline void seg_tr(const float* __restrict__ src, float* __restrict__ dst, int i) {
  int co = i / CiK; int cik = i - co * CiK;
  dst[cik * Co + co] = src[i];
}

__global__ void wtrans_all(
  const float* __restrict__ b1w, const float* __restrict__ c1w,
  const float* __restrict__ b2w, const float* __restrict__ c2w,
  const float* __restrict__ b3w, const float* __restrict__ b4w,
  const float* __restrict__ c3w,
  float* __restrict__ wp1b, float* __restrict__ wp1c,
  float* __restrict__ wp2b, float* __restrict__ wp2c,
  float* __restrict__ wp3b, float* __restrict__ wt4b, float* __restrict__ wt3c)
{
  int j = blockIdx.x * blockDim.x + threadIdx.x;
  if (j < 1179648) { seg_pack<256, 512>(b1w, wp1b, j); return; } j -= 1179648;
  if (j < 1179648) { seg_pack<256, 512>(c1w, wp1c, j); return; } j -= 1179648;
  if (j < 294912)  { seg_pack<128, 256>(b2w, wp2b, j); return; } j -= 294912;
  if (j < 294912)  { seg_pack<128, 256>(c2w, wp2c, j); return; } j -= 294912;
  if (j < 147456)  { seg_pack<128, 128>(b3w, wp3b, j); return; } j -= 147456;
  if (j < 4608)    { seg_tr<36, 128>(b4w, wt4b, j); return; }  j -= 4608;
  if (j < 1152)    { seg_tr<9, 128>(c3w, wt3c, j); return; }
}

// ---------------- split-K partial conv3x3 (LDS tile, no bias/GELU/GN) ----------------
// Lane layout: col = tid&15; r = tid>>4 (pixel row, active r<14). COPT co/lane.
// COPT=4 + 4 blocks/CU: per-CU per-ci VALU 4032 cyc vs LDS 2304 cyc -> VALU-bound,
// 4 waves/SIMD hide LDS/VMEM latency (R5 failed at 2 waves/SIMD; R4 was LDS-bound).
template<int COPT>
__global__ __launch_bounds__(256, 4) void conv3x3_part(
    const float* __restrict__ in0, const float* __restrict__ in1,
    const float* __restrict__ wt0, const float* __restrict__ wt1,
    float* __restrict__ po0, float* __restrict__ po1,
    int Cin, int Cout, int cobPerHead, int cinPerSplit, size_t sStride)
{
  const int tid = threadIdx.x;
  const int bx  = blockIdx.x;
  const int b   = blockIdx.y;
  const int s   = blockIdx.z;
  const int head = bx / cobPerHead;
  const int cob  = bx - head * cobPerHead;
  const float* in  = head ? in1  : in0;
  const float* wt  = head ? wt1  : wt0;
  float* po        = head ? po1  : po0;
  const int co0 = cob * (16 * COPT);

  const int col = tid & 15;
  const int r   = tid >> 4;
  const int co  = co0 + col;
  const bool ract = r < 14;

  __shared__ float tile[2][CHUNK][16][16];   // zero-halo tiles, 32 KB

  {
    float* tz = &tile[0][0][0][0];
    for (int i = tid; i < 2 * CHUNK * 256; i += 256) tz[i] = 0.0f;
  }
  __syncthreads();

  const int p = tid;
  const bool pa = p < 196;
  const int prow = p / 14, pcol = p - prow * 14;
  const float* inb = in + (size_t)b * Cin * 196;
  const int cb0 = (s * cinPerSplit) / CHUNK;
  const int nch = cinPerSplit / CHUNK;

  if (pa) {
#pragma unroll
    for (int ci = 0; ci < CHUNK; ++ci)
      tile[0][ci][prow + 1][pcol + 1] = inb[(cb0 * CHUNK + ci) * 196 + p];
  }
  __syncthreads();

  float acc[COPT][14];
#pragma unroll
  for (int c = 0; c < COPT; ++c)
#pragma unroll
    for (int j = 0; j < 14; ++j) acc[c][j] = 0.0f;

  for (int lcb = 0; lcb < nch; ++lcb) {
    const int cbg = cb0 + lcb;
    const int cur = lcb & 1;
    const bool more = (lcb + 1 < nch);
    float v[CHUNK];
    if (more && pa) {
#pragma unroll
      for (int ci = 0; ci < CHUNK; ++ci)
        v[ci] = inb[((cbg + 1) * CHUNK + ci) * 196 + p];
    }
    if (ract) {
      for (int ci = 0; ci < CHUNK; ++ci) {
        const float4* wq = (const float4*)(wt + ((size_t)(cbg * CHUNK + ci) * Cout + co) * 12);
        float wv[COPT][12];
#pragma unroll
        for (int c = 0; c < COPT; ++c) {
          float4 w0 = wq[c * 48 + 0], w1 = wq[c * 48 + 1], w2 = wq[c * 48 + 2];
          wv[c][0] = w0.x; wv[c][1] = w0.y; wv[c][2]  = w0.z; wv[c][3]  = w0.w;
          wv[c][4] = w1.x; wv[c][5] = w1.y; wv[c][6]  = w1.z; wv[c][7]  = w1.w;
          wv[c][8] = w2.x; wv[c][9] = w2.y; wv[c][10] = w2.z; wv[c][11] = w2.w;
        }
        float nb[3][16];
#pragma unroll
        for (int dr = 0; dr < 3; ++dr) {
          const float4* rp = (const float4*)(&tile[cur][ci][r + dr][0]);
          float4 a = rp[0], bq = rp[1], cq = rp[2], dq = rp[3];
          nb[dr][0]  = a.x;  nb[dr][1]  = a.y;  nb[dr][2]  = a.z;  nb[dr][3]  = a.w;
          nb[dr][4]  = bq.x; nb[dr][5]  = bq.y; nb[dr][6]  = bq.z; nb[dr][7]  = bq.w;
          nb[dr][8]  = cq.x; nb[dr][9]  = cq.y; nb[dr][10] = cq.z; nb[dr][11] = cq.w;
          nb[dr][12] = dq.x; nb[dr][13] = dq.y; nb[dr][14] = dq.z; nb[dr][15] = dq.w;
        }
#pragma unroll
        for (int ky = 0; ky < 3; ++ky)
#pragma unroll
          for (int kx = 0; kx < 3; ++kx) {
#pragma unroll
            for (int c = 0; c < COPT; ++c) {
              float w = wv[c][ky * 3 + kx];
#pragma unroll
              for (int j = 0; j < 14; ++j)
                acc[c][j] = fmaf(w, nb[ky][j + kx], acc[c][j]);
            }
          }
      }
    }
    if (more && pa) {
#pragma unroll
      for (int ci = 0; ci < CHUNK; ++ci)
        tile[1 - cur][ci][prow + 1][pcol + 1] = v[ci];
    }
    __syncthreads();
  }

  if (ract) {
#pragma unroll
    for (int c = 0; c < COPT; ++c) {
      const int oc = c * 16 + col;
      float* op = po + (size_t)s * sStride + ((size_t)b * Cout + co0 + oc) * 196 + r * 14;
#pragma unroll
      for (int j = 0; j < 14; ++j) op[j] = acc[c][j];
    }
  }
}

// ---------------- combine partials + bias + GELU + GroupNorm(8ch groups) ----------------
// block: (head*cobPerHead+cob, batch); thread = pixel (196 active); 16 channels/block.
template<int S>
__global__ __launch_bounds__(256) void combine_gn(
    const float* __restrict__ po0, const float* __restrict__ po1,
    const float* __restrict__ bs0, const float* __restrict__ bs1,
    const float* __restrict__ gw0, const float* __restrict__ gw1,
    const float* __restrict__ gb0, const float* __restrict__ gb1,
    float* __restrict__ out0, float* __restrict__ out1,
    int Cout, int cobPerHead, size_t sStride)
{
  const int tid = threadIdx.x, bx = blockIdx.x, b = blockIdx.y;
  const int head = bx / cobPerHead, cob = bx - head * cobPerHead;
  const float* po = head ? po1 : po0;
  const float* bs = head ? bs1 : bs0;
  const float* gw = head ? gw1 : gw0;
  const float* gb = head ? gb1 : gb0;
  float* out      = head ? out1 : out0;
  const int co0 = cob * 16;

  __shared__ float red[4][4];
  __shared__ float stats[4];

  const int p = tid;
  const bool pa = p < 196;
  float v[16];
  float s0 = 0.f, q0 = 0.f, s1 = 0.f, q1 = 0.f;
  if (pa) {
#pragma unroll
    for (int c = 0; c < 16; ++c) {
      const size_t base = ((size_t)b * Cout + co0 + c) * 196 + p;
      float x = bs[co0 + c];
#pragma unroll
      for (int s = 0; s < S; ++s) x += po[base + (size_t)s * sStride];
      float g = 0.5f * x * (1.0f + erff(x * 0.70710678118654752440f));
      v[c] = g;
      if (c < 8) { s0 += g; q0 += g * g; } else { s1 += g; q1 += g * g; }
    }
  }
#pragma unroll
  for (int off = 32; off > 0; off >>= 1) {
    s0 += __shfl_down(s0, off, 64); q0 += __shfl_down(q0, off, 64);
    s1 += __shfl_down(s1, off, 64); q1 += __shfl_down(q1, off, 64);
  }
  const int wave = tid >> 6, lane = tid & 63;
  if (lane == 0) { red[wave][0] = s0; red[wave][1] = q0; red[wave][2] = s1; red[wave][3] = q1; }
  __syncthreads();
  if (tid == 0) {
    float S0 = red[0][0] + red[1][0] + red[2][0] + red[3][0];
    float Q0 = red[0][1] + red[1][1] + red[2][1] + red[3][1];
    float S1 = red[0][2] + red[1][2] + red[2][2] + red[3][2];
    float Q1 = red[0][3] + red[1][3] + red[2][3] + red[3][3];
    float m0 = S0 * (1.0f / 1568.0f);
    float v0 = Q0 * (1.0f / 1568.0f) - m0 * m0;
    float m1 = S1 * (1.0f / 1568.0f);
    float v1 = Q1 * (1.0f / 1568.0f) - m1 * m1;
    stats[0] = m0; stats[1] = 1.0f / sqrtf(v0 + 1e-5f);
    stats[2] = m1; stats[3] = 1.0f / sqrtf(v1 + 1e-5f);
  }
  __syncthreads();
  if (pa) {
    float m0 = stats[0], i0 = stats[1], m1 = stats[2], i1 = stats[3];
#pragma unroll
    for (int c = 0; c < 16; ++c) {
      float m  = (c < 8) ? m0 : m1;
      float iv = (c < 8) ? i0 : i1;
      float y = (v[c] - m) * iv * gw[co0 + c] + gb[co0 + c];
      out[((size_t)b * Cout + co0 + c) * 196 + p] = y;
    }
  }
}

// ---------------- 1x1 heads: bbox (128->36) and cls (128->9, sigmoid) ----------------
__global__ __launch_bounds__(256) void heads_1x1(
    const float* __restrict__ tb, const float* __restrict__ tc,
    const float* __restrict__ wtb, const float* __restrict__ wtc,
    const float* __restrict__ bb,  const float* __restrict__ bc,
    float* __restrict__ bbox, float* __restrict__ conf)
{
  const int b = blockIdx.x, tid = threadIdx.x;
  if (tid >= 196) return;
  const int p = tid;
  float ab[36], ac[9];
#pragma unroll
  for (int o = 0; o < 36; ++o) ab[o] = bb[o];
#pragma unroll
  for (int o = 0; o < 9; ++o) ac[o] = bc[o];
  const float* pb = tb + (size_t)b * 128 * 196 + p;
  const float* pc = tc + (size_t)b * 128 * 196 + p;
  for (int ci = 0; ci < 128; ++ci) {
    float xb = pb[ci * 196];
    float xc = pc[ci * 196];
    const float* wb = wtb + ci * 36;
    const float* wc = wtc + ci * 9;
#pragma unroll
    for (int o = 0; o < 36; ++o) ab[o] = fmaf(wb[o], xb, ab[o]);
#pragma unroll
    for (int o = 0; o < 9; ++o)  ac[o] = fmaf(wc[o], xc, ac[o]);
  }
  const size_t nb = (size_t)b * NN;
#pragma unroll
  for (int a = 0; a < 9; ++a) {
    size_t n = nb + (size_t)p * 9 + a;
#pragma unroll
    for (int d = 0; d < 4; ++d) bbox[n * 4 + d] = ab[a * 4 + d];
    conf[n] = 1.0f / (1.0f + expf(-ac[a]));
  }
}

// ---------------- per-image greedy NMS with early exit at 50 kept ----------------
__global__ __launch_bounds__(256) void nms_kernel(
  const float* __restrict__ bbox, const float* __restrict__ conf, float* __restrict__ out)
{
  const int b = blockIdx.x, tid = threadIdx.x;
  __shared__ unsigned long long key[SORTN];
  __shared__ float sx1[NN], sy1[NN], sx2[NN], sy2[NN], sar[NN], ssc[NN];
  __shared__ unsigned char sup[NN];
  __shared__ int sV, sMin;

  if (tid == 0) sV = 0;
  __syncthreads();
  int cntv = 0;
  const float* cf = conf + (size_t)b * NN;
  for (int i = tid; i < SORTN; i += 256) {
    unsigned long long k;
    if (i < NN) {
      float s = cf[i];
      unsigned rank = (unsigned)(NN - 1 - i);
      if (s > 0.5f) { k = (((unsigned long long)__float_as_uint(s)) << 32) | rank; cntv++; }
      else k = (unsigned long long)rank;
    } else k = 0ull;
    key[i] = k;
  }
  atomicAdd(&sV, cntv);
  __syncthreads();
  const int V = sV;

  for (int kk = 2; kk <= SORTN; kk <<= 1) {
    for (int j = kk >> 1; j > 0; j >>= 1) {
      for (int i = tid; i < SORTN; i += 256) {
        int ixj = i ^ j;
        if (ixj > i) {
          unsigned long long a = key[i], c = key[ixj];
          bool dirDesc = ((i & kk) == 0);
          if ((a < c) == dirDesc) { key[i] = c; key[ixj] = a; }
        }
      }
      __syncthreads();
    }
  }

  const float* bbb = bbox + (size_t)b * NN * 4;
  for (int i = tid; i < V; i += 256) {
    unsigned long long k = key[i];
    int idx = NN - 1 - (int)(unsigned)(k & 0xFFFFFFFFull);
    float s = __uint_as_float((unsigned)(k >> 32));
    const float* bp = bbb + (size_t)idx * 4;
    float x1 = fminf(fmaxf(bp[0], 0.0f), 1.0f);
    float y1 = fminf(fmaxf(bp[1], 0.0f), 1.0f);
    float x2 = fminf(fmaxf(bp[2], 0.0f), 1.0f);
    float y2 = fminf(fmaxf(bp[3], 0.0f), 1.0f);
    sx1[i] = x1; sy1[i] = y1; sx2[i] = x2; sy2[i] = y2;
    sar[i] = (x2 - x1) * (y2 - y1);
    ssc[i] = s;
    sup[i] = 0;
  }
  __syncthreads();

  int kept = 0, cur = 0;
  float* ob = out + (size_t)b * 50 * 5;
  while (kept < 50 && cur < V) {
    int nxt = -1;
    for (int base = cur; base < V; base += 256) {
      if (tid == 0) sMin = 0x7FFFFFFF;
      __syncthreads();
      int i = base + tid;
      if (i < V && !sup[i]) atomicMin(&sMin, i);
      __syncthreads();
      if (sMin != 0x7FFFFFFF) { nxt = sMin; break; }
    }
    if (nxt < 0) break;
    float kx1 = sx1[nxt], ky1 = sy1[nxt], kx2 = sx2[nxt], ky2 = sy2[nxt], ka = sar[nxt];
    if (tid == 0) {
      float* rr = ob + kept * 5;
      rr[0] = kx1; rr[1] = ky1; rr[2] = kx2; rr[3] = ky2; rr[4] = ssc[nxt];
    }
    kept++;
    for (int jj = nxt + 1 + tid; jj < V; jj += 256) {
      if (!sup[jj]) {
        float xx1 = fmaxf(kx1, sx1[jj]);
        float yy1 = fmaxf(ky1, sy1[jj]);
        float xx2 = fminf(kx2, sx2[jj]);
        float yy2 = fminf(ky2, sy2[jj]);
        float inter = fmaxf(xx2 - xx1, 0.0f) * fmaxf(yy2 - yy1, 0.0f);
        float iou = inter / ((ka + sar[jj]) - inter);
        if (!(iou < 0.3f)) sup[jj] = 1;
      }
    }
    cur = nxt + 1;
    __syncthreads();
  }
  for (int rr = kept + tid; rr < 50; rr += 256) {
    float* qq = ob + rr * 5;
    qq[0] = 0.0f; qq[1] = 0.0f; qq[2] = 0.0f; qq[3] = 0.0f; qq[4] = -1.0f;
  }
}

// ---------------- launch ----------------
extern "C" void kernel_launch(void* const* d_in, const int* in_sizes, int n_in,
                              void* d_out, int out_size, void* d_ws, size_t ws_size,
                              hipStream_t stream)
{
  const float* features = (const float*)d_in[0];
  const float* b1w = (const float*)d_in[1];  const float* b1b = (const float*)d_in[2];
  const float* bg1w = (const float*)d_in[3]; const float* bg1b = (const float*)d_in[4];
  const float* b2w = (const float*)d_in[5];  const float* b2b = (const float*)d_in[6];
  const float* bg2w = (const float*)d_in[7]; const float* bg2b = (const float*)d_in[8];
  const float* b3w = (const float*)d_in[9];  const float* b3b = (const float*)d_in[10];
  const float* bg3w = (const float*)d_in[11]; const float* bg3b = (const float*)d_in[12];
  const float* b4w = (const float*)d_in[13]; const float* b4b = (const float*)d_in[14];
  const float* c1w = (const float*)d_in[15]; const float* c1b = (const float*)d_in[16];
  const float* cg1w = (const float*)d_in[17]; const float* cg1b = (const float*)d_in[18];
  const float* c2w = (const float*)d_in[19]; const float* c2b = (const float*)d_in[20];
  const float* cg2w = (const float*)d_in[21]; const float* cg2b = (const float*)d_in[22];
  const float* c3w = (const float*)d_in[23]; const float* c3b = (const float*)d_in[24];

  float* ws = (float*)d_ws;
  float* wp1b = ws; ws += 1572864;   // 512*256*12
  float* wp1c = ws; ws += 1572864;
  float* wp2b = ws; ws += 393216;    // 256*128*12
  float* wp2c = ws; ws += 393216;
  float* wp3b = ws; ws += 196608;    // 128*128*12
  float* wt4b = ws; ws += 4608;
  float* wt3c = ws; ws += 1152;
  float* t1b = ws; ws += 1605632;    // 32*256*196
  float* t1c = ws; ws += 1605632;
  float* t2b = ws; ws += 802816;     // 32*128*196
  float* t2c = ws; ws += 802816;
  float* P   = ws; ws += 12845056;   // partial region, aliased across layers
  float* bbox = ws; ws += 225792;
  float* conf = ws; ws += 56448;
  float* t3b = t1b;                  // alias: t1b dead after conv2 reads it

  wtrans_all<<<12119, 256, 0, stream>>>(b1w, c1w, b2w, c2w, b3w, b4w, c3w,
                                        wp1b, wp1c, wp2b, wp2c, wp3b, wt4b, wt3c);

  // conv1: Cin=512, Cout=256, COPT=4 (64 co/block), S=4 -> 1024 blocks = 4/CU
  {
    const size_t sStr = (size_t)32 * 256 * 196;          // 1605632
    conv3x3_part<4><<<dim3(8, 32, 4), 256, 0, stream>>>(
        features, features, wp1b, wp1c, P, P + 4 * sStr, 512, 256, 4, 128, sStr);
    combine_gn<4><<<dim3(32, 32), 256, 0, stream>>>(
        P, P + 4 * sStr, b1b, c1b, bg1w, cg1w, bg1b, cg1b, t1b, t1c, 256, 16, sStr);
  }
  // conv2: Cin=256, Cout=128, COPT=4, S=8 -> 1024 blocks = 4/CU
  {
    const size_t sStr = (size_t)32 * 128 * 196;          // 802816
    conv3x3_part<4><<<dim3(4, 32, 8), 256, 0, stream>>>(
        t1b, t1c, wp2b, wp2c, P, P + 8 * sStr, 256, 128, 2, 32, sStr);
    combine_gn<8><<<dim3(16, 32), 256, 0, stream>>>(
        P, P + 8 * sStr, b2b, c2b, bg2w, cg2w, bg2b, cg2b, t2b, t2c, 128, 8, sStr);
  }
  // conv3 (bbox only): Cin=128, Cout=128, COPT=2 (32 co/block), S=8 -> 1024 blocks
  {
    const size_t sStr = (size_t)32 * 128 * 196;
    conv3x3_part<2><<<dim3(4, 32, 8), 256, 0, stream>>>(
        t2b, t2b, wp3b, wp3b, P, P, 128, 128, 4, 16, sStr);
    combine_gn<8><<<dim3(8, 32), 256, 0, stream>>>(
        P, P, b3b, b3b, bg3w, bg3w, bg3b, bg3b, t3b, t3b, 128, 8, sStr);
  }

  heads_1x1<<<32, 256, 0, stream>>>(t3b, t2c, wt4b, wt3c, b4b, c3b, bbox, conf);
  nms_kernel<<<32, 256, 0, stream>>>(bbox, conf, (float*)d_out);
}

// Round 8
// 878.345 us; speedup vs baseline: 3.9393x; 1.0403x over previous
//
#include <hip/hip_runtime.h>
#include <hip/hip_bf16.h>
#include <math.h>

#define CHUNK 16
#define NN 1764
#define SORTN 2048

// ---------------- weight packing ----------------
// 3x3 convs:  W[co][ci][3][3] -> Wp[ci][co][12]  (9 taps + 3 pad, dwordx4-friendly)
template<int Co, int Ci>
__device__ inline void seg_pack(const float* __restrict__ src, float* __restrict__ dst, int i) {
  int co = i / (Ci * 9); int rem = i - co * (Ci * 9); int ci = rem / 9; int k = rem - ci * 9;
  dst[((size_t)ci * Co + co) * 12 + k] = src[i];
}
template<int Co, int CiK>
__device__ inline void seg_tr(const float* __restrict__ src, float* __restrict__ dst, int i) {
  int co = i / CiK; int cik = i - co * CiK;
  dst[cik * Co + co] = src[i];
}

__global__ void wtrans_all(
  const float* __restrict__ b1w, const float* __restrict__ c1w,
  const float* __restrict__ b2w, const float* __restrict__ c2w,
  const float* __restrict__ b3w, const float* __restrict__ b4w,
  const float* __restrict__ c3w,
  float* __restrict__ wp1b, float* __restrict__ wp1c,
  float* __restrict__ wp2b, float* __restrict__ wp2c,
  float* __restrict__ wp3b, float* __restrict__ wt4b, float* __restrict__ wt3c)
{
  int j = blockIdx.x * blockDim.x + threadIdx.x;
  if (j < 1179648) { seg_pack<256, 512>(b1w, wp1b, j); return; } j -= 1179648;
  if (j < 1179648) { seg_pack<256, 512>(c1w, wp1c, j); return; } j -= 1179648;
  if (j < 294912)  { seg_pack<128, 256>(b2w, wp2b, j); return; } j -= 294912;
  if (j < 294912)  { seg_pack<128, 256>(c2w, wp2c, j); return; } j -= 294912;
  if (j < 147456)  { seg_pack<128, 128>(b3w, wp3b, j); return; } j -= 147456;
  if (j < 4608)    { seg_tr<36, 128>(b4w, wt4b, j); return; }  j -= 4608;
  if (j < 1152)    { seg_tr<9, 128>(c3w, wt3c, j); return; }
}

// ---------------- split-K partial conv3x3 (LDS tile, no bias/GELU/GN) ----------------
// Lane layout: col = tid&15; r = tid>>4 (pixel row, active r<14). COPT co/lane.
// launch_bounds(256,2): 256-reg budget -> compiler lands at ~84 VGPR, NO spills
// (R7's (256,4) forced VGPR=64 + spill traffic). Occupancy governor is LDS:
// 32.8 KB/block -> 4 blocks/CU; grids sized 1024 = 4/CU exactly.
template<int COPT>
__global__ __launch_bounds__(256, 2) void conv3x3_part(
    const float* __restrict__ in0, const float* __restrict__ in1,
    const float* __restrict__ wt0, const float* __restrict__ wt1,
    float* __restrict__ po0, float* __restrict__ po1,
    int Cin, int Cout, int cobPerHead, int cinPerSplit, size_t sStride)
{
  const int tid = threadIdx.x;
  const int bx  = blockIdx.x;
  const int b   = blockIdx.y;
  const int s   = blockIdx.z;
  const int head = bx / cobPerHead;
  const int cob  = bx - head * cobPerHead;
  const float* in  = head ? in1  : in0;
  const float* wt  = head ? wt1  : wt0;
  float* po        = head ? po1  : po0;
  const int co0 = cob * (16 * COPT);

  const int col = tid & 15;
  const int r   = tid >> 4;
  const int co  = co0 + col;
  const bool ract = r < 14;

  __shared__ float tile[2][CHUNK][16][16];   // zero-halo tiles, 32 KB

  {
    float* tz = &tile[0][0][0][0];
    for (int i = tid; i < 2 * CHUNK * 256; i += 256) tz[i] = 0.0f;
  }
  __syncthreads();

  const int p = tid;
  const bool pa = p < 196;
  const int prow = p / 14, pcol = p - prow * 14;
  const float* inb = in + (size_t)b * Cin * 196;
  const int cb0 = (s * cinPerSplit) / CHUNK;
  const int nch = cinPerSplit / CHUNK;

  if (pa) {
#pragma unroll
    for (int ci = 0; ci < CHUNK; ++ci)
      tile[0][ci][prow + 1][pcol + 1] = inb[(cb0 * CHUNK + ci) * 196 + p];
  }
  __syncthreads();

  float acc[COPT][14];
#pragma unroll
  for (int c = 0; c < COPT; ++c)
#pragma unroll
    for (int j = 0; j < 14; ++j) acc[c][j] = 0.0f;

  for (int lcb = 0; lcb < nch; ++lcb) {
    const int cbg = cb0 + lcb;
    const int cur = lcb & 1;
    const bool more = (lcb + 1 < nch);
    float v[CHUNK];
    if (more && pa) {
#pragma unroll
      for (int ci = 0; ci < CHUNK; ++ci)
        v[ci] = inb[((cbg + 1) * CHUNK + ci) * 196 + p];
    }
    if (ract) {
      for (int ci = 0; ci < CHUNK; ++ci) {
        const float4* wq = (const float4*)(wt + ((size_t)(cbg * CHUNK + ci) * Cout + co) * 12);
        float wv[COPT][12];
#pragma unroll
        for (int c = 0; c < COPT; ++c) {
          float4 w0 = wq[c * 48 + 0], w1 = wq[c * 48 + 1], w2 = wq[c * 48 + 2];
          wv[c][0] = w0.x; wv[c][1] = w0.y; wv[c][2]  = w0.z; wv[c][3]  = w0.w;
          wv[c][4] = w1.x; wv[c][5] = w1.y; wv[c][6]  = w1.z; wv[c][7]  = w1.w;
          wv[c][8] = w2.x; wv[c][9] = w2.y; wv[c][10] = w2.z; wv[c][11] = w2.w;
        }
        float nb[3][16];
#pragma unroll
        for (int dr = 0; dr < 3; ++dr) {
          const float4* rp = (const float4*)(&tile[cur][ci][r + dr][0]);
          float4 a = rp[0], bq = rp[1], cq = rp[2], dq = rp[3];
          nb[dr][0]  = a.x;  nb[dr][1]  = a.y;  nb[dr][2]  = a.z;  nb[dr][3]  = a.w;
          nb[dr][4]  = bq.x; nb[dr][5]  = bq.y; nb[dr][6]  = bq.z; nb[dr][7]  = bq.w;
          nb[dr][8]  = cq.x; nb[dr][9]  = cq.y; nb[dr][10] = cq.z; nb[dr][11] = cq.w;
          nb[dr][12] = dq.x; nb[dr][13] = dq.y; nb[dr][14] = dq.z; nb[dr][15] = dq.w;
        }
#pragma unroll
        for (int ky = 0; ky < 3; ++ky)
#pragma unroll
          for (int kx = 0; kx < 3; ++kx) {
#pragma unroll
            for (int c = 0; c < COPT; ++c) {
              float w = wv[c][ky * 3 + kx];
#pragma unroll
              for (int j = 0; j < 14; ++j)
                acc[c][j] = fmaf(w, nb[ky][j + kx], acc[c][j]);
            }
          }
      }
    }
    if (more && pa) {
#pragma unroll
      for (int ci = 0; ci < CHUNK; ++ci)
        tile[1 - cur][ci][prow + 1][pcol + 1] = v[ci];
    }
    __syncthreads();
  }

  if (ract) {
#pragma unroll
    for (int c = 0; c < COPT; ++c) {
      const int oc = c * 16 + col;
      float* op = po + (size_t)s * sStride + ((size_t)b * Cout + co0 + oc) * 196 + r * 14;
#pragma unroll
      for (int j = 0; j < 14; ++j) op[j] = acc[c][j];
    }
  }
}

// ---------------- combine partials + bias + GELU + GroupNorm(8ch groups) ----------------
template<int S>
__global__ __launch_bounds__(256) void combine_gn(
    const float* __restrict__ po0, const float* __restrict__ po1,
    const float* __restrict__ bs0, const float* __restrict__ bs1,
    const float* __restrict__ gw0, const float* __restrict__ gw1,
    const float* __restrict__ gb0, const float* __restrict__ gb1,
    float* __restrict__ out0, float* __restrict__ out1,
    int Cout, int cobPerHead, size_t sStride)
{
  const int tid = threadIdx.x, bx = blockIdx.x, b = blockIdx.y;
  const int head = bx / cobPerHead, cob = bx - head * cobPerHead;
  const float* po = head ? po1 : po0;
  const float* bs = head ? bs1 : bs0;
  const float* gw = head ? gw1 : gw0;
  const float* gb = head ? gb1 : gb0;
  float* out      = head ? out1 : out0;
  const int co0 = cob * 16;

  __shared__ float red[4][4];
  __shared__ float stats[4];

  const int p = tid;
  const bool pa = p < 196;
  float v[16];
  float s0 = 0.f, q0 = 0.f, s1 = 0.f, q1 = 0.f;
  if (pa) {
#pragma unroll
    for (int c = 0; c < 16; ++c) {
      const size_t base = ((size_t)b * Cout + co0 + c) * 196 + p;
      float x = bs[co0 + c];
#pragma unroll
      for (int s = 0; s < S; ++s) x += po[base + (size_t)s * sStride];
      float g = 0.5f * x * (1.0f + erff(x * 0.70710678118654752440f));
      v[c] = g;
      if (c < 8) { s0 += g; q0 += g * g; } else { s1 += g; q1 += g * g; }
    }
  }
#pragma unroll
  for (int off = 32; off > 0; off >>= 1) {
    s0 += __shfl_down(s0, off, 64); q0 += __shfl_down(q0, off, 64);
    s1 += __shfl_down(s1, off, 64); q1 += __shfl_down(q1, off, 64);
  }
  const int wave = tid >> 6, lane = tid & 63;
  if (lane == 0) { red[wave][0] = s0; red[wave][1] = q0; red[wave][2] = s1; red[wave][3] = q1; }
  __syncthreads();
  if (tid == 0) {
    float S0 = red[0][0] + red[1][0] + red[2][0] + red[3][0];
    float Q0 = red[0][1] + red[1][1] + red[2][1] + red[3][1];
    float S1 = red[0][2] + red[1][2] + red[2][2] + red[3][2];
    float Q1 = red[0][3] + red[1][3] + red[2][3] + red[3][3];
    float m0 = S0 * (1.0f / 1568.0f);
    float v0 = Q0 * (1.0f / 1568.0f) - m0 * m0;
    float m1 = S1 * (1.0f / 1568.0f);
    float v1 = Q1 * (1.0f / 1568.0f) - m1 * m1;
    stats[0] = m0; stats[1] = 1.0f / sqrtf(v0 + 1e-5f);
    stats[2] = m1; stats[3] = 1.0f / sqrtf(v1 + 1e-5f);
  }
  __syncthreads();
  if (pa) {
    float m0 = stats[0], i0 = stats[1], m1 = stats[2], i1 = stats[3];
#pragma unroll
    for (int c = 0; c < 16; ++c) {
      float m  = (c < 8) ? m0 : m1;
      float iv = (c < 8) ? i0 : i1;
      float y = (v[c] - m) * iv * gw[co0 + c] + gb[co0 + c];
      out[((size_t)b * Cout + co0 + c) * 196 + p] = y;
    }
  }
}

// ---------------- 1x1 heads: bbox (128->36) and cls (128->9, sigmoid) ----------------
__global__ __launch_bounds__(256) void heads_1x1(
    const float* __restrict__ tb, const float* __restrict__ tc,
    const float* __restrict__ wtb, const float* __restrict__ wtc,
    const float* __restrict__ bb,  const float* __restrict__ bc,
    float* __restrict__ bbox, float* __restrict__ conf)
{
  const int b = blockIdx.x, tid = threadIdx.x;
  if (tid >= 196) return;
  const int p = tid;
  float ab[36], ac[9];
#pragma unroll
  for (int o = 0; o < 36; ++o) ab[o] = bb[o];
#pragma unroll
  for (int o = 0; o < 9; ++o) ac[o] = bc[o];
  const float* pb = tb + (size_t)b * 128 * 196 + p;
  const float* pc = tc + (size_t)b * 128 * 196 + p;
  for (int ci = 0; ci < 128; ++ci) {
    float xb = pb[ci * 196];
    float xc = pc[ci * 196];
    const float* wb = wtb + ci * 36;
    const float* wc = wtc + ci * 9;
#pragma unroll
    for (int o = 0; o < 36; ++o) ab[o] = fmaf(wb[o], xb, ab[o]);
#pragma unroll
    for (int o = 0; o < 9; ++o)  ac[o] = fmaf(wc[o], xc, ac[o]);
  }
  const size_t nb = (size_t)b * NN;
#pragma unroll
  for (int a = 0; a < 9; ++a) {
    size_t n = nb + (size_t)p * 9 + a;
#pragma unroll
    for (int d = 0; d < 4; ++d) bbox[n * 4 + d] = ab[a * 4 + d];
    conf[n] = 1.0f / (1.0f + expf(-ac[a]));
  }
}

// ---------------- per-image greedy NMS with early exit at 50 kept ----------------
__global__ __launch_bounds__(256) void nms_kernel(
  const float* __restrict__ bbox, const float* __restrict__ conf, float* __restrict__ out)
{
  const int b = blockIdx.x, tid = threadIdx.x;
  __shared__ unsigned long long key[SORTN];
  __shared__ float sx1[NN], sy1[NN], sx2[NN], sy2[NN], sar[NN], ssc[NN];
  __shared__ unsigned char sup[NN];
  __shared__ int sV, sMin;

  if (tid == 0) sV = 0;
  __syncthreads();
  int cntv = 0;
  const float* cf = conf + (size_t)b * NN;
  for (int i = tid; i < SORTN; i += 256) {
    unsigned long long k;
    if (i < NN) {
      float s = cf[i];
      unsigned rank = (unsigned)(NN - 1 - i);
      if (s > 0.5f) { k = (((unsigned long long)__float_as_uint(s)) << 32) | rank; cntv++; }
      else k = (unsigned long long)rank;
    } else k = 0ull;
    key[i] = k;
  }
  atomicAdd(&sV, cntv);
  __syncthreads();
  const int V = sV;

  for (int kk = 2; kk <= SORTN; kk <<= 1) {
    for (int j = kk >> 1; j > 0; j >>= 1) {
      for (int i = tid; i < SORTN; i += 256) {
        int ixj = i ^ j;
        if (ixj > i) {
          unsigned long long a = key[i], c = key[ixj];
          bool dirDesc = ((i & kk) == 0);
          if ((a < c) == dirDesc) { key[i] = c; key[ixj] = a; }
        }
      }
      __syncthreads();
    }
  }

  const float* bbb = bbox + (size_t)b * NN * 4;
  for (int i = tid; i < V; i += 256) {
    unsigned long long k = key[i];
    int idx = NN - 1 - (int)(unsigned)(k & 0xFFFFFFFFull);
    float s = __uint_as_float((unsigned)(k >> 32));
    const float* bp = bbb + (size_t)idx * 4;
    float x1 = fminf(fmaxf(bp[0], 0.0f), 1.0f);
    float y1 = fminf(fmaxf(bp[1], 0.0f), 1.0f);
    float x2 = fminf(fmaxf(bp[2], 0.0f), 1.0f);
    float y2 = fminf(fmaxf(bp[3], 0.0f), 1.0f);
    sx1[i] = x1; sy1[i] = y1; sx2[i] = x2; sy2[i] = y2;
    sar[i] = (x2 - x1) * (y2 - y1);
    ssc[i] = s;
    sup[i] = 0;
  }
  __syncthreads();

  int kept = 0, cur = 0;
  float* ob = out + (size_t)b * 50 * 5;
  while (kept < 50 && cur < V) {
    int nxt = -1;
    for (int base = cur; base < V; base += 256) {
      if (tid == 0) sMin = 0x7FFFFFFF;
      __syncthreads();
      int i = base + tid;
      if (i < V && !sup[i]) atomicMin(&sMin, i);
      __syncthreads();
      if (sMin != 0x7FFFFFFF) { nxt = sMin; break; }
    }
    if (nxt < 0) break;
    float kx1 = sx1[nxt], ky1 = sy1[nxt], kx2 = sx2[nxt], ky2 = sy2[nxt], ka = sar[nxt];
    if (tid == 0) {
      float* rr = ob + kept * 5;
      rr[0] = kx1; rr[1] = ky1; rr[2] = kx2; rr[3] = ky2; rr[4] = ssc[nxt];
    }
    kept++;
    for (int jj = nxt + 1 + tid; jj < V; jj += 256) {
      if (!sup[jj]) {
        float xx1 = fmaxf(kx1, sx1[jj]);
        float yy1 = fmaxf(ky1, sy1[jj]);
        float xx2 = fminf(kx2, sx2[jj]);
        float yy2 = fminf(ky2, sy2[jj]);
        float inter = fmaxf(xx2 - xx1, 0.0f) * fmaxf(yy2 - yy1, 0.0f);
        float iou = inter / ((ka + sar[jj]) - inter);
        if (!(iou < 0.3f)) sup[jj] = 1;
      }
    }
    cur = nxt + 1;
    __syncthreads();
  }
  for (int rr = kept + tid; rr < 50; rr += 256) {
    float* qq = ob + rr * 5;
    qq[0] = 0.0f; qq[1] = 0.0f; qq[2] = 0.0f; qq[3] = 0.0f; qq[4] = -1.0f;
  }
}

// ---------------- launch ----------------
extern "C" void kernel_launch(void* const* d_in, const int* in_sizes, int n_in,
                              void* d_out, int out_size, void* d_ws, size_t ws_size,
                              hipStream_t stream)
{
  const float* features = (const float*)d_in[0];
  const float* b1w = (const float*)d_in[1];  const float* b1b = (const float*)d_in[2];
  const float* bg1w = (const float*)d_in[3]; const float* bg1b = (const float*)d_in[4];
  const float* b2w = (const float*)d_in[5];  const float* b2b = (const float*)d_in[6];
  const float* bg2w = (const float*)d_in[7]; const float* bg2b = (const float*)d_in[8];
  const float* b3w = (const float*)d_in[9];  const float* b3b = (const float*)d_in[10];
  const float* bg3w = (const float*)d_in[11]; const float* bg3b = (const float*)d_in[12];
  const float* b4w = (const float*)d_in[13]; const float* b4b = (const float*)d_in[14];
  const float* c1w = (const float*)d_in[15]; const float* c1b = (const float*)d_in[16];
  const float* cg1w = (const float*)d_in[17]; const float* cg1b = (const float*)d_in[18];
  const float* c2w = (const float*)d_in[19]; const float* c2b = (const float*)d_in[20];
  const float* cg2w = (const float*)d_in[21]; const float* cg2b = (const float*)d_in[22];
  const float* c3w = (const float*)d_in[23]; const float* c3b = (const float*)d_in[24];

  float* ws = (float*)d_ws;
  float* wp1b = ws; ws += 1572864;   // 512*256*12
  float* wp1c = ws; ws += 1572864;
  float* wp2b = ws; ws += 393216;    // 256*128*12
  float* wp2c = ws; ws += 393216;
  float* wp3b = ws; ws += 196608;    // 128*128*12
  float* wt4b = ws; ws += 4608;
  float* wt3c = ws; ws += 1152;
  float* t1b = ws; ws += 1605632;    // 32*256*196
  float* t1c = ws; ws += 1605632;
  float* t2b = ws; ws += 802816;     // 32*128*196
  float* t2c = ws; ws += 802816;
  float* P   = ws; ws += 12845056;   // partial region, aliased across layers
  float* bbox = ws; ws += 225792;
  float* conf = ws; ws += 56448;
  float* t3b = t1b;                  // alias: t1b dead after conv2 reads it

  wtrans_all<<<12119, 256, 0, stream>>>(b1w, c1w, b2w, c2w, b3w, b4w, c3w,
                                        wp1b, wp1c, wp2b, wp2c, wp3b, wt4b, wt3c);

  // conv1: Cin=512, Cout=256, COPT=4 (64 co/block), S=4 -> 1024 blocks = 4/CU (LDS-capped)
  {
    const size_t sStr = (size_t)32 * 256 * 196;          // 1605632
    conv3x3_part<4><<<dim3(8, 32, 4), 256, 0, stream>>>(
        features, features, wp1b, wp1c, P, P + 4 * sStr, 512, 256, 4, 128, sStr);
    combine_gn<4><<<dim3(32, 32), 256, 0, stream>>>(
        P, P + 4 * sStr, b1b, c1b, bg1w, cg1w, bg1b, cg1b, t1b, t1c, 256, 16, sStr);
  }
  // conv2: Cin=256, Cout=128, COPT=4, S=8 -> 1024 blocks = 4/CU
  {
    const size_t sStr = (size_t)32 * 128 * 196;          // 802816
    conv3x3_part<4><<<dim3(4, 32, 8), 256, 0, stream>>>(
        t1b, t1c, wp2b, wp2c, P, P + 8 * sStr, 256, 128, 2, 32, sStr);
    combine_gn<8><<<dim3(16, 32), 256, 0, stream>>>(
        P, P + 8 * sStr, b2b, c2b, bg2w, cg2w, bg2b, cg2b, t2b, t2c, 128, 8, sStr);
  }
  // conv3 (bbox only): Cin=128, Cout=128, COPT=2 (32 co/block), S=8 -> 1024 blocks
  {
    const size_t sStr = (size_t)32 * 128 * 196;
    conv3x3_part<2><<<dim3(4, 32, 8), 256, 0, stream>>>(
        t2b, t2b, wp3b, wp3b, P, P, 128, 128, 4, 16, sStr);
    combine_gn<8><<<dim3(8, 32), 256, 0, stream>>>(
        P, P, b3b, b3b, bg3w, bg3w, bg3b, bg3b, t3b, t3b, 128, 8, sStr);
  }

  heads_1x1<<<32, 256, 0, stream>>>(t3b, t2c, wt4b, wt3c, b4b, c3b, bbox, conf);
  nms_kernel<<<32, 256, 0, stream>>>(bbox, conf, (float*)d_out);
}

// Round 9
// 847.312 us; speedup vs baseline: 4.0836x; 1.0366x over previous
//
#include <hip/hip_runtime.h>
#include <hip/hip_bf16.h>
#include <math.h>

#define CHUNK 16
#define NN 1764
#define SORTN 2048

typedef float v2f __attribute__((ext_vector_type(2)));

// ---------------- weight packing ----------------
// 3x3 convs: W[co][ci][3][3] -> Wpk[ci][p][20] where pair p=(co>>5)*16+(co&15),
// h=(co&31)>>4 selects the float2 half: slot 2*k+h. One dwordx4 = 2 ready float2
// weight pairs for v_pk_fma_f32 (co, co+16 share all nb operands).
template<int Co, int Ci>
__device__ inline void seg_pack_pk(const float* __restrict__ src, float* __restrict__ dst, int i) {
  int co = i / (Ci * 9); int rem = i - co * (Ci * 9); int ci = rem / 9; int k = rem - ci * 9;
  int p = (co >> 5) * 16 + (co & 15);
  int h = (co & 31) >> 4;
  dst[((size_t)ci * (Co >> 1) + p) * 20 + 2 * k + h] = src[i];
}
template<int Co, int CiK>
__device__ inline void seg_tr(const float* __restrict__ src, float* __restrict__ dst, int i) {
  int co = i / CiK; int cik = i - co * CiK;
  dst[cik * Co + co] = src[i];
}

__global__ void wtrans_all(
  const float* __restrict__ b1w, const float* __restrict__ c1w,
  const float* __restrict__ b2w, const float* __restrict__ c2w,
  const float* __restrict__ b3w, const float* __restrict__ b4w,
  const float* __restrict__ c3w,
  float* __restrict__ wp1b, float* __restrict__ wp1c,
  float* __restrict__ wp2b, float* __restrict__ wp2c,
  float* __restrict__ wp3b, float* __restrict__ wt4b, float* __restrict__ wt3c)
{
  int j = blockIdx.x * blockDim.x + threadIdx.x;
  if (j < 1179648) { seg_pack_pk<256, 512>(b1w, wp1b, j); return; } j -= 1179648;
  if (j < 1179648) { seg_pack_pk<256, 512>(c1w, wp1c, j); return; } j -= 1179648;
  if (j < 294912)  { seg_pack_pk<128, 256>(b2w, wp2b, j); return; } j -= 294912;
  if (j < 294912)  { seg_pack_pk<128, 256>(c2w, wp2c, j); return; } j -= 294912;
  if (j < 147456)  { seg_pack_pk<128, 128>(b3w, wp3b, j); return; } j -= 147456;
  if (j < 4608)    { seg_tr<36, 128>(b4w, wt4b, j); return; }  j -= 4608;
  if (j < 1152)    { seg_tr<9, 128>(c3w, wt3c, j); return; }
}

// ---------------- split-K partial conv3x3 (LDS tile + v_pk_fma_f32) ----------------
// Lane: col = tid&15; r = tid>>4 (active r<14). COPT co/lane as COPT/2 (co,co+16)
// pairs -> v2f accumulators; pk_fma halves FMA issue vs R8's scalar path.
// Per-accumulator op order identical to R8 -> bit-identical output.
template<int COPT>
__global__ __launch_bounds__(256, 2) void conv3x3_part(
    const float* __restrict__ in0, const float* __restrict__ in1,
    const float* __restrict__ wt0, const float* __restrict__ wt1,
    float* __restrict__ po0, float* __restrict__ po1,
    int Cin, int Cout, int cobPerHead, int cinPerSplit, size_t sStride)
{
  constexpr int NP = COPT / 2;
  const int tid = threadIdx.x;
  const int bx  = blockIdx.x;
  const int b   = blockIdx.y;
  const int s   = blockIdx.z;
  const int head = bx / cobPerHead;
  const int cob  = bx - head * cobPerHead;
  const float* in  = head ? in1  : in0;
  const float* wt  = head ? wt1  : wt0;
  float* po        = head ? po1  : po0;
  const int co0 = cob * (16 * COPT);

  const int col = tid & 15;
  const int r   = tid >> 4;
  const bool ract = r < 14;

  __shared__ float tile[2][CHUNK][16][16];   // zero-halo tiles, 32 KB

  {
    float* tz = &tile[0][0][0][0];
    for (int i = tid; i < 2 * CHUNK * 256; i += 256) tz[i] = 0.0f;
  }
  __syncthreads();

  const int p = tid;
  const bool pa = p < 196;
  const int prow = p / 14, pcol = p - prow * 14;
  const float* inb = in + (size_t)b * Cin * 196;
  const int cb0 = (s * cinPerSplit) / CHUNK;
  const int nch = cinPerSplit / CHUNK;
  const int CoutH = Cout >> 1;

  // pair indices for this thread's NP pairs
  int pidx[NP];
#pragma unroll
  for (int g = 0; g < NP; ++g) pidx[g] = ((co0 >> 5) + g) * 16 + col;

  if (pa) {
#pragma unroll
    for (int ci = 0; ci < CHUNK; ++ci)
      tile[0][ci][prow + 1][pcol + 1] = inb[(cb0 * CHUNK + ci) * 196 + p];
  }
  __syncthreads();

  v2f acc[NP][14];
#pragma unroll
  for (int g = 0; g < NP; ++g)
#pragma unroll
    for (int j = 0; j < 14; ++j) acc[g][j] = (v2f)(0.0f);

  for (int lcb = 0; lcb < nch; ++lcb) {
    const int cbg = cb0 + lcb;
    const int cur = lcb & 1;
    const bool more = (lcb + 1 < nch);
    float v[CHUNK];
    if (more && pa) {
#pragma unroll
      for (int ci = 0; ci < CHUNK; ++ci)
        v[ci] = inb[((cbg + 1) * CHUNK + ci) * 196 + p];
    }
    if (ract) {
      for (int ci = 0; ci < CHUNK; ++ci) {
        // weights: per pair 5 dwordx4 -> 9 float2 taps
        v2f w2[NP][9];
#pragma unroll
        for (int g = 0; g < NP; ++g) {
          const float4* wq = (const float4*)(wt +
              ((size_t)(cbg * CHUNK + ci) * CoutH + pidx[g]) * 20);
          float4 q0 = wq[0], q1 = wq[1], q2 = wq[2], q3 = wq[3], q4 = wq[4];
          w2[g][0] = (v2f){q0.x, q0.y}; w2[g][1] = (v2f){q0.z, q0.w};
          w2[g][2] = (v2f){q1.x, q1.y}; w2[g][3] = (v2f){q1.z, q1.w};
          w2[g][4] = (v2f){q2.x, q2.y}; w2[g][5] = (v2f){q2.z, q2.w};
          w2[g][6] = (v2f){q3.x, q3.y}; w2[g][7] = (v2f){q3.z, q3.w};
          w2[g][8] = (v2f){q4.x, q4.y};
        }
        float nb[3][16];
#pragma unroll
        for (int dr = 0; dr < 3; ++dr) {
          const float4* rp = (const float4*)(&tile[cur][ci][r + dr][0]);
          float4 a = rp[0], bq = rp[1], cq = rp[2], dq = rp[3];
          nb[dr][0]  = a.x;  nb[dr][1]  = a.y;  nb[dr][2]  = a.z;  nb[dr][3]  = a.w;
          nb[dr][4]  = bq.x; nb[dr][5]  = bq.y; nb[dr][6]  = bq.z; nb[dr][7]  = bq.w;
          nb[dr][8]  = cq.x; nb[dr][9]  = cq.y; nb[dr][10] = cq.z; nb[dr][11] = cq.w;
          nb[dr][12] = dq.x; nb[dr][13] = dq.y; nb[dr][14] = dq.z; nb[dr][15] = dq.w;
        }
#pragma unroll
        for (int ky = 0; ky < 3; ++ky)
#pragma unroll
          for (int kx = 0; kx < 3; ++kx) {
#pragma unroll
            for (int g = 0; g < NP; ++g) {
              v2f w = w2[g][ky * 3 + kx];
#pragma unroll
              for (int j = 0; j < 14; ++j) {
                float s_ = nb[ky][j + kx];
                v2f nbv = (v2f){s_, s_};
                acc[g][j] = __builtin_elementwise_fma(w, nbv, acc[g][j]);
              }
            }
          }
      }
    }
    if (more && pa) {
#pragma unroll
      for (int ci = 0; ci < CHUNK; ++ci)
        tile[1 - cur][ci][prow + 1][pcol + 1] = v[ci];
    }
    __syncthreads();
  }

  if (ract) {
#pragma unroll
    for (int g = 0; g < NP; ++g) {
      const int ocx = 32 * g + col;        // .x -> co0+32g+col
      const int ocy = ocx + 16;            // .y -> co0+32g+16+col
      float* opx = po + (size_t)s * sStride + ((size_t)b * Cout + co0 + ocx) * 196 + r * 14;
      float* opy = po + (size_t)s * sStride + ((size_t)b * Cout + co0 + ocy) * 196 + r * 14;
#pragma unroll
      for (int j = 0; j < 14; ++j) { opx[j] = acc[g][j].x; opy[j] = acc[g][j].y; }
    }
  }
}

// ---------------- combine partials + bias + GELU + GroupNorm(8ch groups) ----------------
template<int S>
__global__ __launch_bounds__(256) void combine_gn(
    const float* __restrict__ po0, const float* __restrict__ po1,
    const float* __restrict__ bs0, const float* __restrict__ bs1,
    const float* __restrict__ gw0, const float* __restrict__ gw1,
    const float* __restrict__ gb0, const float* __restrict__ gb1,
    float* __restrict__ out0, float* __restrict__ out1,
    int Cout, int cobPerHead, size_t sStride)
{
  const int tid = threadIdx.x, bx = blockIdx.x, b = blockIdx.y;
  const int head = bx / cobPerHead, cob = bx - head * cobPerHead;
  const float* po = head ? po1 : po0;
  const float* bs = head ? bs1 : bs0;
  const float* gw = head ? gw1 : gw0;
  const float* gb = head ? gb1 : gb0;
  float* out      = head ? out1 : out0;
  const int co0 = cob * 16;

  __shared__ float red[4][4];
  __shared__ float stats[4];

  const int p = tid;
  const bool pa = p < 196;
  float v[16];
  float s0 = 0.f, q0 = 0.f, s1 = 0.f, q1 = 0.f;
  if (pa) {
#pragma unroll
    for (int c = 0; c < 16; ++c) {
      const size_t base = ((size_t)b * Cout + co0 + c) * 196 + p;
      float x = bs[co0 + c];
#pragma unroll
      for (int s = 0; s < S; ++s) x += po[base + (size_t)s * sStride];
      float g = 0.5f * x * (1.0f + erff(x * 0.70710678118654752440f));
      v[c] = g;
      if (c < 8) { s0 += g; q0 += g * g; } else { s1 += g; q1 += g * g; }
    }
  }
#pragma unroll
  for (int off = 32; off > 0; off >>= 1) {
    s0 += __shfl_down(s0, off, 64); q0 += __shfl_down(q0, off, 64);
    s1 += __shfl_down(s1, off, 64); q1 += __shfl_down(q1, off, 64);
  }
  const int wave = tid >> 6, lane = tid & 63;
  if (lane == 0) { red[wave][0] = s0; red[wave][1] = q0; red[wave][2] = s1; red[wave][3] = q1; }
  __syncthreads();
  if (tid == 0) {
    float S0 = red[0][0] + red[1][0] + red[2][0] + red[3][0];
    float Q0 = red[0][1] + red[1][1] + red[2][1] + red[3][1];
    float S1 = red[0][2] + red[1][2] + red[2][2] + red[3][2];
    float Q1 = red[0][3] + red[1][3] + red[2][3] + red[3][3];
    float m0 = S0 * (1.0f / 1568.0f);
    float v0 = Q0 * (1.0f / 1568.0f) - m0 * m0;
    float m1 = S1 * (1.0f / 1568.0f);
    float v1 = Q1 * (1.0f / 1568.0f) - m1 * m1;
    stats[0] = m0; stats[1] = 1.0f / sqrtf(v0 + 1e-5f);
    stats[2] = m1; stats[3] = 1.0f / sqrtf(v1 + 1e-5f);
  }
  __syncthreads();
  if (pa) {
    float m0 = stats[0], i0 = stats[1], m1 = stats[2], i1 = stats[3];
#pragma unroll
    for (int c = 0; c < 16; ++c) {
      float m  = (c < 8) ? m0 : m1;
      float iv = (c < 8) ? i0 : i1;
      float y = (v[c] - m) * iv * gw[co0 + c] + gb[co0 + c];
      out[((size_t)b * Cout + co0 + c) * 196 + p] = y;
    }
  }
}

// ---------------- 1x1 heads: bbox (128->36) and cls (128->9, sigmoid) ----------------
__global__ __launch_bounds__(256) void heads_1x1(
    const float* __restrict__ tb, const float* __restrict__ tc,
    const float* __restrict__ wtb, const float* __restrict__ wtc,
    const float* __restrict__ bb,  const float* __restrict__ bc,
    float* __restrict__ bbox, float* __restrict__ conf)
{
  const int b = blockIdx.x, tid = threadIdx.x;
  if (tid >= 196) return;
  const int p = tid;
  float ab[36], ac[9];
#pragma unroll
  for (int o = 0; o < 36; ++o) ab[o] = bb[o];
#pragma unroll
  for (int o = 0; o < 9; ++o) ac[o] = bc[o];
  const float* pb = tb + (size_t)b * 128 * 196 + p;
  const float* pc = tc + (size_t)b * 128 * 196 + p;
  for (int ci = 0; ci < 128; ++ci) {
    float xb = pb[ci * 196];
    float xc = pc[ci * 196];
    const float* wb = wtb + ci * 36;
    const float* wc = wtc + ci * 9;
#pragma unroll
    for (int o = 0; o < 36; ++o) ab[o] = fmaf(wb[o], xb, ab[o]);
#pragma unroll
    for (int o = 0; o < 9; ++o)  ac[o] = fmaf(wc[o], xc, ac[o]);
  }
  const size_t nb = (size_t)b * NN;
#pragma unroll
  for (int a = 0; a < 9; ++a) {
    size_t n = nb + (size_t)p * 9 + a;
#pragma unroll
    for (int d = 0; d < 4; ++d) bbox[n * 4 + d] = ab[a * 4 + d];
    conf[n] = 1.0f / (1.0f + expf(-ac[a]));
  }
}

// ---------------- per-image greedy NMS with early exit at 50 kept ----------------
__global__ __launch_bounds__(256) void nms_kernel(
  const float* __restrict__ bbox, const float* __restrict__ conf, float* __restrict__ out)
{
  const int b = blockIdx.x, tid = threadIdx.x;
  __shared__ unsigned long long key[SORTN];
  __shared__ float sx1[NN], sy1[NN], sx2[NN], sy2[NN], sar[NN], ssc[NN];
  __shared__ unsigned char sup[NN];
  __shared__ int sV, sMin;

  if (tid == 0) sV = 0;
  __syncthreads();
  int cntv = 0;
  const float* cf = conf + (size_t)b * NN;
  for (int i = tid; i < SORTN; i += 256) {
    unsigned long long k;
    if (i < NN) {
      float s = cf[i];
      unsigned rank = (unsigned)(NN - 1 - i);
      if (s > 0.5f) { k = (((unsigned long long)__float_as_uint(s)) << 32) | rank; cntv++; }
      else k = (unsigned long long)rank;
    } else k = 0ull;
    key[i] = k;
  }
  atomicAdd(&sV, cntv);
  __syncthreads();
  const int V = sV;

  for (int kk = 2; kk <= SORTN; kk <<= 1) {
    for (int j = kk >> 1; j > 0; j >>= 1) {
      for (int i = tid; i < SORTN; i += 256) {
        int ixj = i ^ j;
        if (ixj > i) {
          unsigned long long a = key[i], c = key[ixj];
          bool dirDesc = ((i & kk) == 0);
          if ((a < c) == dirDesc) { key[i] = c; key[ixj] = a; }
        }
      }
      __syncthreads();
    }
  }

  const float* bbb = bbox + (size_t)b * NN * 4;
  for (int i = tid; i < V; i += 256) {
    unsigned long long k = key[i];
    int idx = NN - 1 - (int)(unsigned)(k & 0xFFFFFFFFull);
    float s = __uint_as_float((unsigned)(k >> 32));
    const float* bp = bbb + (size_t)idx * 4;
    float x1 = fminf(fmaxf(bp[0], 0.0f), 1.0f);
    float y1 = fminf(fmaxf(bp[1], 0.0f), 1.0f);
    float x2 = fminf(fmaxf(bp[2], 0.0f), 1.0f);
    float y2 = fminf(fmaxf(bp[3], 0.0f), 1.0f);
    sx1[i] = x1; sy1[i] = y1; sx2[i] = x2; sy2[i] = y2;
    sar[i] = (x2 - x1) * (y2 - y1);
    ssc[i] = s;
    sup[i] = 0;
  }
  __syncthreads();

  int kept = 0, cur = 0;
  float* ob = out + (size_t)b * 50 * 5;
  while (kept < 50 && cur < V) {
    int nxt = -1;
    for (int base = cur; base < V; base += 256) {
      if (tid == 0) sMin = 0x7FFFFFFF;
      __syncthreads();
      int i = base + tid;
      if (i < V && !sup[i]) atomicMin(&sMin, i);
      __syncthreads();
      if (sMin != 0x7FFFFFFF) { nxt = sMin; break; }
    }
    if (nxt < 0) break;
    float kx1 = sx1[nxt], ky1 = sy1[nxt], kx2 = sx2[nxt], ky2 = sy2[nxt], ka = sar[nxt];
    if (tid == 0) {
      float* rr = ob + kept * 5;
      rr[0] = kx1; rr[1] = ky1; rr[2] = kx2; rr[3] = ky2; rr[4] = ssc[nxt];
    }
    kept++;
    for (int jj = nxt + 1 + tid; jj < V; jj += 256) {
      if (!sup[jj]) {
        float xx1 = fmaxf(kx1, sx1[jj]);
        float yy1 = fmaxf(ky1, sy1[jj]);
        float xx2 = fminf(kx2, sx2[jj]);
        float yy2 = fminf(ky2, sy2[jj]);
        float inter = fmaxf(xx2 - xx1, 0.0f) * fmaxf(yy2 - yy1, 0.0f);
        float iou = inter / ((ka + sar[jj]) - inter);
        if (!(iou < 0.3f)) sup[jj] = 1;
      }
    }
    cur = nxt + 1;
    __syncthreads();
  }
  for (int rr = kept + tid; rr < 50; rr += 256) {
    float* qq = ob + rr * 5;
    qq[0] = 0.0f; qq[1] = 0.0f; qq[2] = 0.0f; qq[3] = 0.0f; qq[4] = -1.0f;
  }
}

// ---------------- launch ----------------
extern "C" void kernel_launch(void* const* d_in, const int* in_sizes, int n_in,
                              void* d_out, int out_size, void* d_ws, size_t ws_size,
                              hipStream_t stream)
{
  const float* features = (const float*)d_in[0];
  const float* b1w = (const float*)d_in[1];  const float* b1b = (const float*)d_in[2];
  const float* bg1w = (const float*)d_in[3]; const float* bg1b = (const float*)d_in[4];
  const float* b2w = (const float*)d_in[5];  const float* b2b = (const float*)d_in[6];
  const float* bg2w = (const float*)d_in[7]; const float* bg2b = (const float*)d_in[8];
  const float* b3w = (const float*)d_in[9];  const float* b3b = (const float*)d_in[10];
  const float* bg3w = (const float*)d_in[11]; const float* bg3b = (const float*)d_in[12];
  const float* b4w = (const float*)d_in[13]; const float* b4b = (const float*)d_in[14];
  const float* c1w = (const float*)d_in[15]; const float* c1b = (const float*)d_in[16];
  const float* cg1w = (const float*)d_in[17]; const float* cg1b = (const float*)d_in[18];
  const float* c2w = (const float*)d_in[19]; const float* c2b = (const float*)d_in[20];
  const float* cg2w = (const float*)d_in[21]; const float* cg2b = (const float*)d_in[22];
  const float* c3w = (const float*)d_in[23]; const float* c3b = (const float*)d_in[24];

  float* ws = (float*)d_ws;
  float* wp1b = ws; ws += 1310720;   // 512*128*20
  float* wp1c = ws; ws += 1310720;
  float* wp2b = ws; ws += 327680;    // 256*64*20
  float* wp2c = ws; ws += 327680;
  float* wp3b = ws; ws += 163840;    // 128*64*20
  float* wt4b = ws; ws += 4608;
  float* wt3c = ws; ws += 1152;
  float* t1b = ws; ws += 1605632;    // 32*256*196
  float* t1c = ws; ws += 1605632;
  float* t2b = ws; ws += 802816;     // 32*128*196
  float* t2c = ws; ws += 802816;
  float* P   = ws; ws += 12845056;   // partial region, aliased across layers
  float* bbox = ws; ws += 225792;
  float* conf = ws; ws += 56448;
  float* t3b = t1b;                  // alias: t1b dead after conv2 reads it

  wtrans_all<<<12119, 256, 0, stream>>>(b1w, c1w, b2w, c2w, b3w, b4w, c3w,
                                        wp1b, wp1c, wp2b, wp2c, wp3b, wt4b, wt3c);

  // conv1: Cin=512, Cout=256, COPT=4 (64 co/block), S=4 -> 1024 blocks
  {
    const size_t sStr = (size_t)32 * 256 * 196;          // 1605632
    conv3x3_part<4><<<dim3(8, 32, 4), 256, 0, stream>>>(
        features, features, wp1b, wp1c, P, P + 4 * sStr, 512, 256, 4, 128, sStr);
    combine_gn<4><<<dim3(32, 32), 256, 0, stream>>>(
        P, P + 4 * sStr, b1b, c1b, bg1w, cg1w, bg1b, cg1b, t1b, t1c, 256, 16, sStr);
  }
  // conv2: Cin=256, Cout=128, COPT=4, S=8 -> 1024 blocks
  {
    const size_t sStr = (size_t)32 * 128 * 196;          // 802816
    conv3x3_part<4><<<dim3(4, 32, 8), 256, 0, stream>>>(
        t1b, t1c, wp2b, wp2c, P, P + 8 * sStr, 256, 128, 2, 32, sStr);
    combine_gn<8><<<dim3(16, 32), 256, 0, stream>>>(
        P, P + 8 * sStr, b2b, c2b, bg2w, cg2w, bg2b, cg2b, t2b, t2c, 128, 8, sStr);
  }
  // conv3 (bbox only): Cin=128, Cout=128, COPT=2 (32 co/block), S=8 -> 1024 blocks
  {
    const size_t sStr = (size_t)32 * 128 * 196;
    conv3x3_part<2><<<dim3(4, 32, 8), 256, 0, stream>>>(
        t2b, t2b, wp3b, wp3b, P, P, 128, 128, 4, 16, sStr);
    combine_gn<8><<<dim3(8, 32), 256, 0, stream>>>(
        P, P, b3b, b3b, bg3w, bg3w, bg3b, bg3b, t3b, t3b, 128, 8, sStr);
  }

  heads_1x1<<<32, 256, 0, stream>>>(t3b, t2c, wt4b, wt3c, b4b, c3b, bbox, conf);
  nms_kernel<<<32, 256, 0, stream>>>(bbox, conf, (float*)d_out);
}

// Round 11
// 776.956 us; speedup vs baseline: 4.4534x; 1.0906x over previous
//
#include <hip/hip_runtime.h>
#include <hip/hip_bf16.h>
#include <math.h>

#define CHUNK 16
#define NN 1764
#define SORTN 2048

typedef float v2f __attribute__((ext_vector_type(2)));

// ---------------- weight packing ----------------
// 3x3 convs: W[co][ci][3][3] -> Wpk[ci][p][20], pair p=(co>>5)*16+(co&15),
// h=(co&31)>>4 -> slot 2*k+h. One dwordx4 = 2 float2 pairs for v_pk_fma_f32.
template<int Co, int Ci>
__device__ inline void seg_pack_pk(const float* __restrict__ src, float* __restrict__ dst, int i) {
  int co = i / (Ci * 9); int rem = i - co * (Ci * 9); int ci = rem / 9; int k = rem - ci * 9;
  int p = (co >> 5) * 16 + (co & 15);
  int h = (co & 31) >> 4;
  dst[((size_t)ci * (Co >> 1) + p) * 20 + 2 * k + h] = src[i];
}
template<int Co, int CiK>
__device__ inline void seg_tr(const float* __restrict__ src, float* __restrict__ dst, int i) {
  int co = i / CiK; int cik = i - co * CiK;
  dst[cik * Co + co] = src[i];
}

__global__ void wtrans_all(
  const float* __restrict__ b1w, const float* __restrict__ c1w,
  const float* __restrict__ b2w, const float* __restrict__ c2w,
  const float* __restrict__ b3w, const float* __restrict__ b4w,
  const float* __restrict__ c3w,
  float* __restrict__ wp1b, float* __restrict__ wp1c,
  float* __restrict__ wp2b, float* __restrict__ wp2c,
  float* __restrict__ wp3b, float* __restrict__ wt4b, float* __restrict__ wt3c)
{
  int j = blockIdx.x * blockDim.x + threadIdx.x;
  if (j < 1179648) { seg_pack_pk<256, 512>(b1w, wp1b, j); return; } j -= 1179648;
  if (j < 1179648) { seg_pack_pk<256, 512>(c1w, wp1c, j); return; } j -= 1179648;
  if (j < 294912)  { seg_pack_pk<128, 256>(b2w, wp2b, j); return; } j -= 294912;
  if (j < 294912)  { seg_pack_pk<128, 256>(c2w, wp2c, j); return; } j -= 294912;
  if (j < 147456)  { seg_pack_pk<128, 128>(b3w, wp3b, j); return; } j -= 147456;
  if (j < 4608)    { seg_tr<36, 128>(b4w, wt4b, j); return; }  j -= 4608;
  if (j < 1152)    { seg_tr<9, 128>(c3w, wt3c, j); return; }
}

// ---------------- split-K partial conv3x3 (LDS tile + v_pk_fma_f32) — R9 verified ----------------
// NOTE (R10 post-mortem): MFMA/bf16x3 conv is precision-blocked here — scores cluster
// at the 0.5 validity threshold; ~1e-5 logit error flips NMS decisions. Keep fp32.
template<int COPT>
__global__ __launch_bounds__(256, 2) void conv3x3_part(
    const float* __restrict__ in0, const float* __restrict__ in1,
    const float* __restrict__ wt0, const float* __restrict__ wt1,
    float* __restrict__ po0, float* __restrict__ po1,
    int Cin, int Cout, int cobPerHead, int cinPerSplit, size_t sStride)
{
  constexpr int NP = COPT / 2;
  const int tid = threadIdx.x;
  const int bx  = blockIdx.x;
  const int b   = blockIdx.y;
  const int s   = blockIdx.z;
  const int head = bx / cobPerHead;
  const int cob  = bx - head * cobPerHead;
  const float* in  = head ? in1  : in0;
  const float* wt  = head ? wt1  : wt0;
  float* po        = head ? po1  : po0;
  const int co0 = cob * (16 * COPT);

  const int col = tid & 15;
  const int r   = tid >> 4;
  const bool ract = r < 14;

  __shared__ float tile[2][CHUNK][16][16];

  {
    float* tz = &tile[0][0][0][0];
    for (int i = tid; i < 2 * CHUNK * 256; i += 256) tz[i] = 0.0f;
  }
  __syncthreads();

  const int p = tid;
  const bool pa = p < 196;
  const int prow = p / 14, pcol = p - prow * 14;
  const float* inb = in + (size_t)b * Cin * 196;
  const int cb0 = (s * cinPerSplit) / CHUNK;
  const int nch = cinPerSplit / CHUNK;
  const int CoutH = Cout >> 1;

  int pidx[NP];
#pragma unroll
  for (int g = 0; g < NP; ++g) pidx[g] = ((co0 >> 5) + g) * 16 + col;

  if (pa) {
#pragma unroll
    for (int ci = 0; ci < CHUNK; ++ci)
      tile[0][ci][prow + 1][pcol + 1] = inb[(cb0 * CHUNK + ci) * 196 + p];
  }
  __syncthreads();

  v2f acc[NP][14];
#pragma unroll
  for (int g = 0; g < NP; ++g)
#pragma unroll
    for (int j = 0; j < 14; ++j) acc[g][j] = (v2f)(0.0f);

  for (int lcb = 0; lcb < nch; ++lcb) {
    const int cbg = cb0 + lcb;
    const int cur = lcb & 1;
    const bool more = (lcb + 1 < nch);
    float v[CHUNK];
    if (more && pa) {
#pragma unroll
      for (int ci = 0; ci < CHUNK; ++ci)
        v[ci] = inb[((cbg + 1) * CHUNK + ci) * 196 + p];
    }
    if (ract) {
      for (int ci = 0; ci < CHUNK; ++ci) {
        v2f w2[NP][9];
#pragma unroll
        for (int g = 0; g < NP; ++g) {
          const float4* wq = (const float4*)(wt +
              ((size_t)(cbg * CHUNK + ci) * CoutH + pidx[g]) * 20);
          float4 q0 = wq[0], q1 = wq[1], q2 = wq[2], q3 = wq[3], q4 = wq[4];
          w2[g][0] = (v2f){q0.x, q0.y}; w2[g][1] = (v2f){q0.z, q0.w};
          w2[g][2] = (v2f){q1.x, q1.y}; w2[g][3] = (v2f){q1.z, q1.w};
          w2[g][4] = (v2f){q2.x, q2.y}; w2[g][5] = (v2f){q2.z, q2.w};
          w2[g][6] = (v2f){q3.x, q3.y}; w2[g][7] = (v2f){q3.z, q3.w};
          w2[g][8] = (v2f){q4.x, q4.y};
        }
        float nb[3][16];
#pragma unroll
        for (int dr = 0; dr < 3; ++dr) {
          const float4* rp = (const float4*)(&tile[cur][ci][r + dr][0]);
          float4 a = rp[0], bq = rp[1], cq = rp[2], dq = rp[3];
          nb[dr][0]  = a.x;  nb[dr][1]  = a.y;  nb[dr][2]  = a.z;  nb[dr][3]  = a.w;
          nb[dr][4]  = bq.x; nb[dr][5]  = bq.y; nb[dr][6]  = bq.z; nb[dr][7]  = bq.w;
          nb[dr][8]  = cq.x; nb[dr][9]  = cq.y; nb[dr][10] = cq.z; nb[dr][11] = cq.w;
          nb[dr][12] = dq.x; nb[dr][13] = dq.y; nb[dr][14] = dq.z; nb[dr][15] = dq.w;
        }
#pragma unroll
        for (int ky = 0; ky < 3; ++ky)
#pragma unroll
          for (int kx = 0; kx < 3; ++kx) {
#pragma unroll
            for (int g = 0; g < NP; ++g) {
              v2f w = w2[g][ky * 3 + kx];
#pragma unroll
              for (int j = 0; j < 14; ++j) {
                float s_ = nb[ky][j + kx];
                v2f nbv = (v2f){s_, s_};
                acc[g][j] = __builtin_elementwise_fma(w, nbv, acc[g][j]);
              }
            }
          }
      }
    }
    if (more && pa) {
#pragma unroll
      for (int ci = 0; ci < CHUNK; ++ci)
        tile[1 - cur][ci][prow + 1][pcol + 1] = v[ci];
    }
    __syncthreads();
  }

  if (ract) {
#pragma unroll
    for (int g = 0; g < NP; ++g) {
      const int ocx = 32 * g + col;
      const int ocy = ocx + 16;
      float* opx = po + (size_t)s * sStride + ((size_t)b * Cout + co0 + ocx) * 196 + r * 14;
      float* opy = po + (size_t)s * sStride + ((size_t)b * Cout + co0 + ocy) * 196 + r * 14;
#pragma unroll
      for (int j = 0; j < 14; ++j) { opx[j] = acc[g][j].x; opy[j] = acc[g][j].y; }
    }
  }
}

// ---------------- combine partials + bias + GELU + GroupNorm(8ch groups) ----------------
template<int S>
__global__ __launch_bounds__(256) void combine_gn(
    const float* __restrict__ po0, const float* __restrict__ po1,
    const float* __restrict__ bs0, const float* __restrict__ bs1,
    const float* __restrict__ gw0, const float* __restrict__ gw1,
    const float* __restrict__ gb0, const float* __restrict__ gb1,
    float* __restrict__ out0, float* __restrict__ out1,
    int Cout, int cobPerHead, size_t sStride)
{
  const int tid = threadIdx.x, bx = blockIdx.x, b = blockIdx.y;
  const int head = bx / cobPerHead, cob = bx - head * cobPerHead;
  const float* po = head ? po1 : po0;
  const float* bs = head ? bs1 : bs0;
  const float* gw = head ? gw1 : gw0;
  const float* gb = head ? gb1 : gb0;
  float* out      = head ? out1 : out0;
  const int co0 = cob * 16;

  __shared__ float red[4][4];
  __shared__ float stats[4];

  const int p = tid;
  const bool pa = p < 196;
  float v[16];
  float s0 = 0.f, q0 = 0.f, s1 = 0.f, q1 = 0.f;
  if (pa) {
#pragma unroll
    for (int c = 0; c < 16; ++c) {
      const size_t base = ((size_t)b * Cout + co0 + c) * 196 + p;
      float x = bs[co0 + c];
#pragma unroll
      for (int s = 0; s < S; ++s) x += po[base + (size_t)s * sStride];
      float g = 0.5f * x * (1.0f + erff(x * 0.70710678118654752440f));
      v[c] = g;
      if (c < 8) { s0 += g; q0 += g * g; } else { s1 += g; q1 += g * g; }
    }
  }
#pragma unroll
  for (int off = 32; off > 0; off >>= 1) {
    s0 += __shfl_down(s0, off, 64); q0 += __shfl_down(q0, off, 64);
    s1 += __shfl_down(s1, off, 64); q1 += __shfl_down(q1, off, 64);
  }
  const int wave = tid >> 6, lane = tid & 63;
  if (lane == 0) { red[wave][0] = s0; red[wave][1] = q0; red[wave][2] = s1; red[wave][3] = q1; }
  __syncthreads();
  if (tid == 0) {
    float S0 = red[0][0] + red[1][0] + red[2][0] + red[3][0];
    float Q0 = red[0][1] + red[1][1] + red[2][1] + red[3][1];
    float S1 = red[0][2] + red[1][2] + red[2][2] + red[3][2];
    float Q1 = red[0][3] + red[1][3] + red[2][3] + red[3][3];
    float m0 = S0 * (1.0f / 1568.0f);
    float v0 = Q0 * (1.0f / 1568.0f) - m0 * m0;
    float m1 = S1 * (1.0f / 1568.0f);
    float v1 = Q1 * (1.0f / 1568.0f) - m1 * m1;
    stats[0] = m0; stats[1] = 1.0f / sqrtf(v0 + 1e-5f);
    stats[2] = m1; stats[3] = 1.0f / sqrtf(v1 + 1e-5f);
  }
  __syncthreads();
  if (pa) {
    float m0 = stats[0], i0 = stats[1], m1 = stats[2], i1 = stats[3];
#pragma unroll
    for (int c = 0; c < 16; ++c) {
      float m  = (c < 8) ? m0 : m1;
      float iv = (c < 8) ? i0 : i1;
      float y = (v[c] - m) * iv * gw[co0 + c] + gb[co0 + c];
      out[((size_t)b * Cout + co0 + c) * 196 + p] = y;
    }
  }
}

// ---------------- 1x1 heads, re-gridded: (b, og) blocks; og 0-3 = bbox 9-out chunks, og 4 = conf ----------------
__global__ __launch_bounds__(256) void heads_1x1(
    const float* __restrict__ tb, const float* __restrict__ tc,
    const float* __restrict__ wtb, const float* __restrict__ wtc, // [128][36], [128][9]
    const float* __restrict__ bb,  const float* __restrict__ bc,
    float* __restrict__ bbox, float* __restrict__ conf)
{
  const int b = blockIdx.x, og = blockIdx.y, tid = threadIdx.x;
  if (tid >= 196) return;
  const int p = tid;
  const bool isConf = (og == 4);
  const float* in = isConf ? tc : tb;
  const float* wbase = isConf ? wtc : (wtb + og * 9);
  const int wstride = isConf ? 9 : 36;
  const float* bsrc = isConf ? bc : (bb + og * 9);

  float a[9];
#pragma unroll
  for (int o = 0; o < 9; ++o) a[o] = bsrc[o];
  const float* pin = in + (size_t)b * 128 * 196 + p;
  for (int ci = 0; ci < 128; ++ci) {
    float x = pin[ci * 196];
    const float* w = wbase + ci * wstride;   // uniform -> s_load
#pragma unroll
    for (int o = 0; o < 9; ++o) a[o] = fmaf(w[o], x, a[o]);
  }
  if (isConf) {
    float* cf = conf + (size_t)b * NN + (size_t)p * 9;
#pragma unroll
    for (int o = 0; o < 9; ++o) cf[o] = 1.0f / (1.0f + expf(-a[o]));
  } else {
    float* bp = bbox + ((size_t)b * NN) * 4 + (size_t)p * 36 + og * 9;
#pragma unroll
    for (int o = 0; o < 9; ++o) bp[o] = a[o];
  }
}

// ---------------- per-image greedy NMS, 512 threads ----------------
__global__ __launch_bounds__(512) void nms_kernel(
  const float* __restrict__ bbox, const float* __restrict__ conf, float* __restrict__ out)
{
  const int b = blockIdx.x, tid = threadIdx.x;
  __shared__ unsigned long long key[SORTN];
  __shared__ float sx1[NN], sy1[NN], sx2[NN], sy2[NN], sar[NN], ssc[NN];
  __shared__ unsigned char sup[NN];
  __shared__ int sV, sMin;

  if (tid == 0) sV = 0;
  __syncthreads();
  int cntv = 0;
  const float* cf = conf + (size_t)b * NN;
  for (int i = tid; i < SORTN; i += 512) {
    unsigned long long k;
    if (i < NN) {
      float s = cf[i];
      unsigned rank = (unsigned)(NN - 1 - i);
      if (s > 0.5f) { k = (((unsigned long long)__float_as_uint(s)) << 32) | rank; cntv++; }
      else k = (unsigned long long)rank;
    } else k = 0ull;
    key[i] = k;
  }
  atomicAdd(&sV, cntv);
  __syncthreads();
  const int V = sV;

  for (int kk = 2; kk <= SORTN; kk <<= 1) {
    for (int j = kk >> 1; j > 0; j >>= 1) {
      for (int i = tid; i < SORTN; i += 512) {
        int ixj = i ^ j;
        if (ixj > i) {
          unsigned long long a = key[i], c = key[ixj];
          bool dirDesc = ((i & kk) == 0);
          if ((a < c) == dirDesc) { key[i] = c; key[ixj] = a; }
        }
      }
      __syncthreads();
    }
  }

  const float* bbb = bbox + (size_t)b * NN * 4;
  for (int i = tid; i < V; i += 512) {
    unsigned long long k = key[i];
    int idx = NN - 1 - (int)(unsigned)(k & 0xFFFFFFFFull);
    float s = __uint_as_float((unsigned)(k >> 32));
    const float* bp = bbb + (size_t)idx * 4;
    float x1 = fminf(fmaxf(bp[0], 0.0f), 1.0f);
    float y1 = fminf(fmaxf(bp[1], 0.0f), 1.0f);
    float x2 = fminf(fmaxf(bp[2], 0.0f), 1.0f);
    float y2 = fminf(fmaxf(bp[3], 0.0f), 1.0f);
    sx1[i] = x1; sy1[i] = y1; sx2[i] = x2; sy2[i] = y2;
    sar[i] = (x2 - x1) * (y2 - y1);
    ssc[i] = s;
    sup[i] = 0;
  }
  __syncthreads();

  int kept = 0, cur = 0;
  float* ob = out + (size_t)b * 50 * 5;
  while (kept < 50 && cur < V) {
    int nxt = -1;
    for (int base = cur; base < V; base += 512) {
      if (tid == 0) sMin = 0x7FFFFFFF;
      __syncthreads();
      int i = base + tid;
      if (i < V && !sup[i]) atomicMin(&sMin, i);
      __syncthreads();
      if (sMin != 0x7FFFFFFF) { nxt = sMin; break; }
    }
    if (nxt < 0) break;
    float kx1 = sx1[nxt], ky1 = sy1[nxt], kx2 = sx2[nxt], ky2 = sy2[nxt], ka = sar[nxt];
    if (tid == 0) {
      float* rr = ob + kept * 5;
      rr[0] = kx1; rr[1] = ky1; rr[2] = kx2; rr[3] = ky2; rr[4] = ssc[nxt];
    }
    kept++;
    for (int jj = nxt + 1 + tid; jj < V; jj += 512) {
      if (!sup[jj]) {
        float xx1 = fmaxf(kx1, sx1[jj]);
        float yy1 = fmaxf(ky1, sy1[jj]);
        float xx2 = fminf(kx2, sx2[jj]);
        float yy2 = fminf(ky2, sy2[jj]);
        float inter = fmaxf(xx2 - xx1, 0.0f) * fmaxf(yy2 - yy1, 0.0f);
        float iou = inter / ((ka + sar[jj]) - inter);
        if (!(iou < 0.3f)) sup[jj] = 1;
      }
    }
    cur = nxt + 1;
    __syncthreads();
  }
  for (int rr = kept + tid; rr < 50; rr += 512) {
    float* qq = ob + rr * 5;
    qq[0] = 0.0f; qq[1] = 0.0f; qq[2] = 0.0f; qq[3] = 0.0f; qq[4] = -1.0f;
  }
}

// ---------------- launch ----------------
extern "C" void kernel_launch(void* const* d_in, const int* in_sizes, int n_in,
                              void* d_out, int out_size, void* d_ws, size_t ws_size,
                              hipStream_t stream)
{
  const float* features = (const float*)d_in[0];
  const float* b1w = (const float*)d_in[1];  const float* b1b = (const float*)d_in[2];
  const float* bg1w = (const float*)d_in[3]; const float* bg1b = (const float*)d_in[4];
  const float* b2w = (const float*)d_in[5];  const float* b2b = (const float*)d_in[6];
  const float* bg2w = (const float*)d_in[7]; const float* bg2b = (const float*)d_in[8];
  const float* b3w = (const float*)d_in[9];  const float* b3b = (const float*)d_in[10];
  const float* bg3w = (const float*)d_in[11]; const float* bg3b = (const float*)d_in[12];
  const float* b4w = (const float*)d_in[13]; const float* b4b = (const float*)d_in[14];
  const float* c1w = (const float*)d_in[15]; const float* c1b = (const float*)d_in[16];
  const float* cg1w = (const float*)d_in[17]; const float* cg1b = (const float*)d_in[18];
  const float* c2w = (const float*)d_in[19]; const float* c2b = (const float*)d_in[20];
  const float* cg2w = (const float*)d_in[21]; const float* cg2b = (const float*)d_in[22];
  const float* c3w = (const float*)d_in[23]; const float* c3b = (const float*)d_in[24];

  float* ws = (float*)d_ws;
  float* wp1b = ws; ws += 1310720;   // 512*128*20
  float* wp1c = ws; ws += 1310720;
  float* wp2b = ws; ws += 327680;    // 256*64*20
  float* wp2c = ws; ws += 327680;
  float* wp3b = ws; ws += 163840;    // 128*64*20
  float* wt4b = ws; ws += 4608;
  float* wt3c = ws; ws += 1152;
  float* t1b = ws; ws += 1605632;    // 32*256*196
  float* t1c = ws; ws += 1605632;
  float* t2b = ws; ws += 802816;     // 32*128*196
  float* t2c = ws; ws += 802816;
  float* P   = ws; ws += 12845056;   // partial region, aliased across layers
  float* bbox = ws; ws += 225792;
  float* conf = ws; ws += 56448;
  float* t3b = t1b;                  // alias: t1b dead after conv2 reads it

  wtrans_all<<<12119, 256, 0, stream>>>(b1w, c1w, b2w, c2w, b3w, b4w, c3w,
                                        wp1b, wp1c, wp2b, wp2c, wp3b, wt4b, wt3c);

  // conv1: Cin=512, Cout=256, COPT=4 (64 co/block), S=4 -> 1024 blocks
  {
    const size_t sStr = (size_t)32 * 256 * 196;          // 1605632
    conv3x3_part<4><<<dim3(8, 32, 4), 256, 0, stream>>>(
        features, features, wp1b, wp1c, P, P + 4 * sStr, 512, 256, 4, 128, sStr);
    combine_gn<4><<<dim3(32, 32), 256, 0, stream>>>(
        P, P + 4 * sStr, b1b, c1b, bg1w, cg1w, bg1b, cg1b, t1b, t1c, 256, 16, sStr);
  }
  // conv2: Cin=256, Cout=128, COPT=4, S=8 -> 1024 blocks
  {
    const size_t sStr = (size_t)32 * 128 * 196;          // 802816
    conv3x3_part<4><<<dim3(4, 32, 8), 256, 0, stream>>>(
        t1b, t1c, wp2b, wp2c, P, P + 8 * sStr, 256, 128, 2, 32, sStr);
    combine_gn<8><<<dim3(16, 32), 256, 0, stream>>>(
        P, P + 8 * sStr, b2b, c2b, bg2w, cg2w, bg2b, cg2b, t2b, t2c, 128, 8, sStr);
  }
  // conv3 (bbox only): Cin=128, Cout=128, COPT=2, S=8 -> 1024 blocks
  {
    const size_t sStr = (size_t)32 * 128 * 196;
    conv3x3_part<2><<<dim3(4, 32, 8), 256, 0, stream>>>(
        t2b, t2b, wp3b, wp3b, P, P, 128, 128, 4, 16, sStr);
    combine_gn<8><<<dim3(8, 32), 256, 0, stream>>>(
        P, P, b3b, b3b, bg3w, bg3w, bg3b, bg3b, t3b, t3b, 128, 8, sStr);
  }

  heads_1x1<<<dim3(32, 5), 256, 0, stream>>>(t3b, t2c, wt4b, wt3c, b4b, c3b, bbox, conf);
  nms_kernel<<<32, 512, 0, stream>>>(bbox, conf, (float*)d_out);
}